// Round 8
// baseline (2321.654 us; speedup 1.0000x reference)
//
#include <hip/hip_runtime.h>

#define LNEPS 1e-5f

typedef unsigned short ushort_t;
typedef __attribute__((ext_vector_type(8))) short short8;   // bf16x8 MFMA frag
typedef __attribute__((ext_vector_type(4))) float f32x4;    // fp32x4 accum frag

__device__ inline unsigned short f2b(float f) {
    union { float f; unsigned int u; } c; c.f = f;
    unsigned int u = c.u;
    unsigned int r = (u + 0x7FFFu + ((u >> 16) & 1u)) >> 16;  // RNE
    return (unsigned short)r;
}

// ---------------------------------------------------------------------------
// Weight packing into MFMA fragment order (wave-contiguous 1KB loads).
// w1P: [L][c=32][kb=8][lane][8]; K=256 = [ed 0..127 | nd_j 0..127]
//      frag elem: col = c*16+(lane&15); kl = kb*32+(lane>>4)*8+e;
//      W1 row = kl<128 ? kl : kl+128   (skips the hoisted nd_i rows 128..255)
// w2P: [L][c2=8][kbg=16][lane][8]; natural k-order.
// Used as the A-operand (M dim = hidden col) in swapped-order MFMA.
// ---------------------------------------------------------------------------
__global__ void k_convw(const float* __restrict__ w1, const float* __restrict__ w2,
                        ushort_t* __restrict__ w1P, ushort_t* __restrict__ w2P) {
    int idx = blockIdx.x * 256 + threadIdx.x;   // chunk index (8 elems each)
    if (idx < 65536) {
        int l = idx >> 14, r = idx & 16383;
        int c = r >> 9;  r &= 511;
        int kb = r >> 6, lane = r & 63;
        int col = c * 16 + (lane & 15);
        int k0 = kb * 32 + (lane >> 4) * 8;
        ushort_t o[8];
        #pragma unroll
        for (int e = 0; e < 8; ++e) {
            int kl = k0 + e;
            int row = kl < 128 ? kl : kl + 128;
            o[e] = f2b(w1[((size_t)l * 384 + row) * 512 + col]);
        }
        *(uint4*)(w1P + (size_t)idx * 8) = *(uint4*)o;
    }
    if (idx < 32768) {
        int l = idx >> 13, r = idx & 8191;
        int c2 = r >> 10; r &= 1023;
        int kbg = r >> 6, lane = r & 63;
        int col = c2 * 16 + (lane & 15);
        int k0 = kbg * 32 + (lane >> 4) * 8;
        ushort_t o[8];
        #pragma unroll
        for (int e = 0; e < 8; ++e)
            o[e] = f2b(w2[((size_t)l * 512 + k0 + e) * 128 + col]);
        *(uint4*)(w2P + (size_t)idx * 8) = *(uint4*)o;
    }
}

// ---------------------------------------------------------------------------
// Edge init: dist, adj, edges = relu(LN(dist*ee_w + ee_b)), edb bf16 mirror,
// and msgs_0 = adj * dot(edges_row, nodes[i]).   one wave per row.
// ---------------------------------------------------------------------------
__global__ void k_init(const float* __restrict__ coords, const float* __restrict__ nodes,
                       const float* __restrict__ ee_w, const float* __restrict__ ee_b,
                       const float* __restrict__ ee_g, const float* __restrict__ ee_bt,
                       float* __restrict__ ed, ushort_t* __restrict__ edb,
                       float* __restrict__ adjf, float* __restrict__ msgs) {
    int r = blockIdx.x * 4 + (threadIdx.x >> 6);
    int lane = threadIdx.x & 63;
    int i = r >> 8, j = r & 255;
    float dx = coords[i * 3 + 0] - coords[j * 3 + 0];
    float dy = coords[i * 3 + 1] - coords[j * 3 + 1];
    float dz = coords[i * 3 + 2] - coords[j * 3 + 2];
    float sq = dx * dx + dy * dy + dz * dz;
    float dist = sq > 0.f ? sqrtf(sq) : 0.f;
    float adjv = dist < 10.f ? 1.f : 0.f;
    if (lane == 0) adjf[r] = adjv;
    float e0 = dist * ee_w[lane] + ee_b[lane];
    float e1 = dist * ee_w[lane + 64] + ee_b[lane + 64];
    float s = e0 + e1, q = e0 * e0 + e1 * e1;
    #pragma unroll
    for (int off = 1; off < 64; off <<= 1) {
        s += __shfl_xor(s, off, 64);
        q += __shfl_xor(q, off, 64);
    }
    float mean = s * (1.f / 128.f);
    float var = q * (1.f / 128.f) - mean * mean;
    float rs = rsqrtf(var + LNEPS);
    float e0r = fmaxf((e0 - mean) * rs * ee_g[lane] + ee_bt[lane], 0.f);
    float e1r = fmaxf((e1 - mean) * rs * ee_g[lane + 64] + ee_bt[lane + 64], 0.f);
    ed[(size_t)r * 128 + lane]       = e0r;
    ed[(size_t)r * 128 + lane + 64]  = e1r;
    edb[(size_t)r * 128 + lane]      = f2b(e0r);
    edb[(size_t)r * 128 + lane + 64] = f2b(e1r);
    float d = e0r * nodes[(i << 7) + lane] + e1r * nodes[(i << 7) + 64 + lane];
    #pragma unroll
    for (int off = 1; off < 64; off <<= 1) d += __shfl_xor(d, off, 64);
    if (lane == 0) msgs[r] = adjv * d;
}

// ---------------------------------------------------------------------------
// Per-layer node precompute (fp32):
//   cI[p][t] = b1[t] + sum_k nd[p][k] * W1[(128+k)][t]
// also ndb[p][*] = bf16(nd[p][*]).   one block per node p, 512 threads.
// ---------------------------------------------------------------------------
__global__ __launch_bounds__(512) void k_pre(
    const float* __restrict__ nd, const float* __restrict__ W1,
    const float* __restrict__ b1,
    float* __restrict__ cI, ushort_t* __restrict__ ndb) {
    __shared__ float ndl[128];
    int p = blockIdx.x, t = threadIdx.x;
    if (t < 128) {
        float v = nd[(size_t)p * 128 + t];
        ndl[t] = v;
        ndb[(size_t)p * 128 + t] = f2b(v);
    }
    __syncthreads();
    const float* wm = W1 + (size_t)128 * 512 + t;
    float a1 = b1[t];
    #pragma unroll 4
    for (int k = 0; k < 128; ++k) a1 += ndl[k] * wm[(size_t)k * 512];
    cI[(size_t)p * 512 + t] = a1;
}

// ---------------------------------------------------------------------------
// Generic fp32 row-MLP: out = [res +] relu(LN(concat(in0,in1) @ W1 + b1)) @ W2 + b2
// one block (512 threads) per row; K = w0 + w1n <= 384; O <= 128
// ---------------------------------------------------------------------------
__global__ __launch_bounds__(512) void k_mlp(
    const float* __restrict__ in0, int w0, const float* __restrict__ in1, int w1n,
    const float* __restrict__ W1, const float* __restrict__ b1,
    const float* __restrict__ g, const float* __restrict__ bt,
    const float* __restrict__ W2, const float* __restrict__ b2, int O,
    const float* __restrict__ res, float* __restrict__ out) {
    __shared__ float ni[384];
    __shared__ float hsh[512];
    __shared__ float part[4][128];
    __shared__ float red[16];
    int row = blockIdx.x;
    int t = threadIdx.x;
    int K = w0 + w1n;
    if (t < w0) ni[t] = in0[(size_t)row * w0 + t];
    else if (t < K) ni[t] = in1[(size_t)row * w1n + (t - w0)];
    __syncthreads();
    float acc = b1[t];
    #pragma unroll 4
    for (int k = 0; k < K; ++k) acc += ni[k] * W1[(size_t)k * 512 + t];
    float s = acc, q = acc * acc;
    #pragma unroll
    for (int off = 1; off < 64; off <<= 1) {
        s += __shfl_xor(s, off, 64);
        q += __shfl_xor(q, off, 64);
    }
    int wv = t >> 6;
    if ((t & 63) == 0) { red[wv] = s; red[8 + wv] = q; }
    __syncthreads();
    float S = 0.f, Q = 0.f;
    #pragma unroll
    for (int w = 0; w < 8; ++w) { S += red[w]; Q += red[8 + w]; }
    float mean = S * (1.f / 512.f);
    float var = Q * (1.f / 512.f) - mean * mean;
    float rs = rsqrtf(var + LNEPS);
    hsh[t] = fmaxf((acc - mean) * rs * g[t] + bt[t], 0.f);
    __syncthreads();
    int qd = t >> 7, c = t & 127;
    float pacc = 0.f;
    if (c < O) {
        #pragma unroll 4
        for (int kk = 0; kk < 128; ++kk)
            pacc += hsh[qd * 128 + kk] * W2[(size_t)(qd * 128 + kk) * O + c];
    }
    part[qd][c] = pacc;
    __syncthreads();
    if (t < O) {
        float v = part[0][t] + part[1][t] + part[2][t] + part[3][t] + b2[t];
        if (res) v += res[(size_t)row * O + t];
        out[(size_t)row * O + t] = v;
    }
}

// ---------------------------------------------------------------------------
// Fused edge update (in-place on ed + edb mirror) + msgs for next layer.
// bf16 MFMA, SWAPPED operand order: D[hidden-col][edge-row].
// Block: 512 threads (8 waves), 64 edge rows; i fixed, j = jbase + row.
// GEMM1: wave w -> 64 hidden cols, acc[4][4].
// GEMM2: K-split over two 32KB h-halves (cols 0..255 then 256..511); acc2[4]
//        carried across halves; h-half reuses the dead stage region.
// LDS 36.5KB: stage/h-half [64][512B] swz @0 (32KB),
//             red [8][64][2] f32 @32768 (reused as msum), stats [64][2] @36864
// 4 blocks/CU (32 waves/CU).
// ---------------------------------------------------------------------------
__global__ __launch_bounds__(512, 8) void k_edge(
    float* ed, ushort_t* edb, const ushort_t* __restrict__ ndb,
    const float* __restrict__ cIg, const ushort_t* __restrict__ w1P,
    const float* __restrict__ g, const float* __restrict__ bt,
    const ushort_t* __restrict__ w2P, const float* __restrict__ b2,
    const float* __restrict__ ndn, const float* __restrict__ adjf,
    float* __restrict__ msgs) {
    __shared__ char smem[37376];
    const int tid = threadIdx.x;
    const int w = tid >> 6, lane = tid & 63;
    const int l15 = lane & 15, lhi = lane >> 4;
    const int rbase = blockIdx.x * 64;
    const int ib = rbase >> 8;          // fixed node i for this block
    const int jbase = rbase & 255;

    // ---- stage ei = [edb | ndb] bf16 : 64 rows x 32 chunks(16B), XOR-swz row&7
    #pragma unroll
    for (int it = 0; it < 4; ++it) {
        int c = tid + it * 512;
        int row = c >> 5, q = c & 31;
        uint4 pk;
        if (q < 16) pk = *(const uint4*)(edb + (size_t)(rbase + row) * 128 + q * 8);
        else        pk = *(const uint4*)(ndb + (size_t)(jbase + row) * 128 + (q - 16) * 8);
        *(uint4*)(smem + row * 512 + ((q ^ (row & 7)) * 16)) = pk;
    }
    __syncthreads();

    // ---- GEMM1 (swapped): acc[m][n] = D[hcol][edgerow], K=256
    f32x4 acc[4][4];
    f32x4 zero = {0.f, 0.f, 0.f, 0.f};
    #pragma unroll
    for (int m = 0; m < 4; ++m)
        #pragma unroll
        for (int n = 0; n < 4; ++n) acc[m][n] = zero;

    const int cw = w * 64;
    #pragma unroll 2
    for (int kb = 0; kb < 8; ++kb) {
        short8 a[4];
        #pragma unroll
        for (int m = 0; m < 4; ++m) {
            int row = m * 16 + l15;
            a[m] = *(const short8*)(smem + row * 512 + (((kb * 4 + lhi) ^ (row & 7)) * 16));
        }
        #pragma unroll
        for (int n = 0; n < 4; ++n) {
            short8 b = *(const short8*)(w1P + ((((w * 4 + n) * 8 + kb) << 6) + lane) * 8);
            #pragma unroll
            for (int m = 0; m < 4; ++m)
                acc[m][n] = __builtin_amdgcn_mfma_f32_16x16x32_bf16(b, a[m], acc[m][n], 0, 0, 0);
        }
    }
    // acc[m][n][e]: edge row = m*16+l15, hidden col = cw + n*16 + lhi*4 + e

    // ---- add cI (float4, i fixed), per-row stats (rows in l15 -> 2 shfl only)
    float* red = (float*)(smem + 32768);     // [8][64][2]
    float* stats = (float*)(smem + 36864);   // [64][2]
    {
        float4 ci[4];
        #pragma unroll
        for (int n = 0; n < 4; ++n)
            ci[n] = *(const float4*)(cIg + (size_t)ib * 512 + cw + n * 16 + lhi * 4);
        #pragma unroll
        for (int m = 0; m < 4; ++m) {
            float s = 0.f, q = 0.f;
            #pragma unroll
            for (int n = 0; n < 4; ++n) {
                float v0 = acc[m][n][0] + ci[n].x;
                float v1 = acc[m][n][1] + ci[n].y;
                float v2 = acc[m][n][2] + ci[n].z;
                float v3 = acc[m][n][3] + ci[n].w;
                acc[m][n][0] = v0; acc[m][n][1] = v1;
                acc[m][n][2] = v2; acc[m][n][3] = v3;
                s += v0 + v1 + v2 + v3;
                q += v0 * v0 + v1 * v1 + v2 * v2 + v3 * v3;
            }
            s += __shfl_xor(s, 16, 64);
            s += __shfl_xor(s, 32, 64);
            q += __shfl_xor(q, 16, 64);
            q += __shfl_xor(q, 32, 64);
            if (lhi == 0) {
                red[(w * 64 + m * 16 + l15) * 2 + 0] = s;
                red[(w * 64 + m * 16 + l15) * 2 + 1] = q;
            }
        }
    }
    __syncthreads();
    if (tid < 64) {
        float S = 0.f, Q = 0.f;
        #pragma unroll
        for (int ww = 0; ww < 8; ++ww) {
            S += red[(ww * 64 + tid) * 2 + 0];
            Q += red[(ww * 64 + tid) * 2 + 1];
        }
        float mean = S * (1.f / 512.f);
        float var = Q * (1.f / 512.f) - mean * mean;
        stats[tid * 2 + 0] = mean;
        stats[tid * 2 + 1] = rsqrtf(var + LNEPS);
    }
    __syncthreads();

    // ---- LN apply + relu (in registers)
    {
        float4 gg[4], bb[4];
        #pragma unroll
        for (int n = 0; n < 4; ++n) {
            gg[n] = *(const float4*)(g + cw + n * 16 + lhi * 4);
            bb[n] = *(const float4*)(bt + cw + n * 16 + lhi * 4);
        }
        #pragma unroll
        for (int m = 0; m < 4; ++m) {
            int row = m * 16 + l15;
            float mean = stats[row * 2 + 0];
            float rs = stats[row * 2 + 1];
            #pragma unroll
            for (int n = 0; n < 4; ++n) {
                acc[m][n][0] = fmaxf((acc[m][n][0] - mean) * rs * gg[n].x + bb[n].x, 0.f);
                acc[m][n][1] = fmaxf((acc[m][n][1] - mean) * rs * gg[n].y + bb[n].y, 0.f);
                acc[m][n][2] = fmaxf((acc[m][n][2] - mean) * rs * gg[n].z + bb[n].z, 0.f);
                acc[m][n][3] = fmaxf((acc[m][n][3] - mean) * rs * gg[n].w + bb[n].w, 0.f);
            }
        }
    }

    // ---- GEMM2 (swapped), K-split over two h-halves; wave -> (rt, ch2)
    const int rt = w >> 1, ch2 = w & 1;
    const int arow = rt * 16 + l15;
    f32x4 acc2[4];
    #pragma unroll
    for (int n2 = 0; n2 < 4; ++n2) acc2[n2] = zero;

    #pragma unroll
    for (int hf = 0; hf < 2; ++hf) {
        // store h-half: waves with (w>>2)==hf own cols hf*256 .. hf*256+255
        if ((w >> 2) == hf) {
            const int base = (w & 3) * 64;
            #pragma unroll
            for (int m = 0; m < 4; ++m) {
                int row = m * 16 + l15;
                #pragma unroll
                for (int n = 0; n < 4; ++n) {
                    int p0 = base + n * 16 + lhi * 4;
                    int addr = row * 512 + ((((p0 >> 3) ^ (row & 7))) * 16) + (p0 & 7) * 2;
                    uint2 pk;
                    pk.x = (unsigned)f2b(acc[m][n][0]) | ((unsigned)f2b(acc[m][n][1]) << 16);
                    pk.y = (unsigned)f2b(acc[m][n][2]) | ((unsigned)f2b(acc[m][n][3]) << 16);
                    *(uint2*)(smem + addr) = pk;
                }
            }
        }
        __syncthreads();
        // GEMM2 partial: K = 256 of this half
        #pragma unroll 2
        for (int kbg = 0; kbg < 8; ++kbg) {
            short8 a = *(const short8*)(smem + arow * 512 + (((kbg * 4 + lhi) ^ (arow & 7)) * 16));
            #pragma unroll
            for (int n2 = 0; n2 < 4; ++n2) {
                short8 b = *(const short8*)(w2P + ((((ch2 * 4 + n2) * 16 + hf * 8 + kbg) << 6) + lane) * 8);
                acc2[n2] = __builtin_amdgcn_mfma_f32_16x16x32_bf16(b, a, acc2[n2], 0, 0, 0);
            }
        }
        __syncthreads();   // half's h reads done before overwrite / msum reuse
    }

    // ---- epilogue: float4 residual RMW, edb mirror, fused msgs partial
    float partial = 0.f;
    {
        const int row = rt * 16 + l15;
        #pragma unroll
        for (int n2 = 0; n2 < 4; ++n2) {
            int col0 = ch2 * 64 + n2 * 16 + lhi * 4;
            size_t goff = (size_t)(rbase + row) * 128 + col0;
            float4 r4 = *(const float4*)(ed + goff);
            float4 b4 = *(const float4*)(b2 + col0);
            float4 n4 = *(const float4*)(ndn + (size_t)ib * 128 + col0);
            float o0 = acc2[n2][0] + b4.x + r4.x;
            float o1 = acc2[n2][1] + b4.y + r4.y;
            float o2 = acc2[n2][2] + b4.z + r4.z;
            float o3 = acc2[n2][3] + b4.w + r4.w;
            float4 o4 = {o0, o1, o2, o3};
            *(float4*)(ed + goff) = o4;
            uint2 pk;
            pk.x = (unsigned)f2b(o0) | ((unsigned)f2b(o1) << 16);
            pk.y = (unsigned)f2b(o2) | ((unsigned)f2b(o3) << 16);
            *(uint2*)(edb + goff) = pk;
            partial += o0 * n4.x + o1 * n4.y + o2 * n4.z + o3 * n4.w;
        }
    }
    partial += __shfl_xor(partial, 16, 64);
    partial += __shfl_xor(partial, 32, 64);
    float* msum = (float*)(smem + 32768);   // reuse red region (dead)
    if (lhi == 0) msum[ch2 * 64 + rt * 16 + l15] = partial;
    __syncthreads();
    if (tid < 64) msgs[rbase + tid] = adjf[rbase + tid] * (msum[tid] + msum[64 + tid]);
}

// ---------------------------------------------------------------------------
extern "C" void kernel_launch(void* const* d_in, const int* in_sizes, int n_in,
                              void* d_out, int out_size, void* d_ws, size_t ws_size,
                              hipStream_t stream) {
    const float* nodes  = (const float*)d_in[0];
    const float* coords = (const float*)d_in[1];
    const float* ee_w   = (const float*)d_in[2];
    const float* ee_b   = (const float*)d_in[3];
    const float* ee_g   = (const float*)d_in[4];
    const float* ee_bt  = (const float*)d_in[5];
    const float* nu1_w  = (const float*)d_in[6];
    const float* nu1_b  = (const float*)d_in[7];
    const float* nu_g   = (const float*)d_in[8];
    const float* nu_bt  = (const float*)d_in[9];
    const float* nu2_w  = (const float*)d_in[10];
    const float* nu2_b  = (const float*)d_in[11];
    const float* eu1_w  = (const float*)d_in[12];
    const float* eu1_b  = (const float*)d_in[13];
    const float* eu_g   = (const float*)d_in[14];
    const float* eu_bt  = (const float*)d_in[15];
    const float* eu2_w  = (const float*)d_in[16];
    const float* eu2_b  = (const float*)d_in[17];
    const float* sp1_w  = (const float*)d_in[18];
    const float* sp1_b  = (const float*)d_in[19];
    const float* sp_g   = (const float*)d_in[20];
    const float* sp_bt  = (const float*)d_in[21];
    const float* sp2_w  = (const float*)d_in[22];
    const float* sp2_b  = (const float*)d_in[23];
    const float* no1_w  = (const float*)d_in[24];
    const float* no1_b  = (const float*)d_in[25];
    const float* no_g   = (const float*)d_in[26];
    const float* no_bt  = (const float*)d_in[27];
    const float* no2_w  = (const float*)d_in[28];
    const float* no2_b  = (const float*)d_in[29];

    char* p = (char*)d_ws;
    float* ed      = (float*)p;     p += (size_t)65536 * 128 * 4;   // 33.5 MB
    ushort_t* edb  = (ushort_t*)p;  p += (size_t)65536 * 128 * 2;   // 16.8 MB
    float* ndA     = (float*)p;     p += 256 * 128 * 4;
    float* ndB     = (float*)p;     p += 256 * 128 * 4;
    ushort_t* ndb  = (ushort_t*)p;  p += 256 * 128 * 2;
    float* msgs    = (float*)p;     p += 65536 * 4;
    float* adjf    = (float*)p;     p += 65536 * 4;
    float* cI      = (float*)p;     p += 256 * 512 * 4;
    ushort_t* w1P  = (ushort_t*)p;  p += (size_t)4 * 131072 * 2;    // 1 MB
    ushort_t* w2P  = (ushort_t*)p;  p += (size_t)4 * 65536 * 2;     // 512 KB

    k_convw<<<256, 256, 0, stream>>>(eu1_w, eu2_w, w1P, w2P);
    k_init<<<16384, 256, 0, stream>>>(coords, nodes, ee_w, ee_b, ee_g, ee_bt,
                                      ed, edb, adjf, msgs);

    const float* nd_cur = nodes;
    float* nd_bufs[2] = {ndA, ndB};
    for (int l = 0; l < 4; ++l) {
        float* nd_next = nd_bufs[l & 1];
        k_pre<<<256, 512, 0, stream>>>(nd_cur, eu1_w + (size_t)l * 384 * 512,
                                       eu1_b + l * 512, cI, ndb);
        k_mlp<<<256, 512, 0, stream>>>(nd_cur, 128, msgs, 256,
            nu1_w + (size_t)l * 384 * 512, nu1_b + l * 512, nu_g + l * 512, nu_bt + l * 512,
            nu2_w + (size_t)l * 512 * 128, nu2_b + l * 128, 128, nd_cur, nd_next);
        k_edge<<<1024, 512, 0, stream>>>(ed, edb, ndb, cI,
            w1P + (size_t)l * 131072, eu_g + l * 512, eu_bt + l * 512,
            w2P + (size_t)l * 65536, eu2_b + l * 128,
            nd_next, adjf, msgs);
        nd_cur = nd_next;
    }

    float* out_nodes  = (float*)d_out;
    float* out_coords = out_nodes + 32768;
    k_mlp<<<256, 512, 0, stream>>>(nd_cur, 128, nullptr, 0,
        no1_w, no1_b, no_g, no_bt, no2_w, no2_b, 128, nullptr, out_nodes);
    k_mlp<<<256, 512, 0, stream>>>(out_nodes, 128, nullptr, 0,
        sp1_w, sp1_b, sp_g, sp_bt, sp2_w, sp2_b, 3, nullptr, out_coords);
}

// Round 9
// 654.727 us; speedup vs baseline: 3.5460x; 3.5460x over previous
//
#include <hip/hip_runtime.h>

#define LNEPS 1e-5f

typedef unsigned short ushort_t;
typedef __attribute__((ext_vector_type(8))) short short8;   // bf16x8 MFMA frag
typedef __attribute__((ext_vector_type(4))) float f32x4;    // fp32x4 accum frag

__device__ inline unsigned short f2b(float f) {
    union { float f; unsigned int u; } c; c.f = f;
    unsigned int u = c.u;
    unsigned int r = (u + 0x7FFFu + ((u >> 16) & 1u)) >> 16;  // RNE
    return (unsigned short)r;
}

// ---------------------------------------------------------------------------
// Weight packing into MFMA fragment order (wave-contiguous 1KB loads).
// w1P: [L][c=32][kb=8][lane][8]; K=256 = [ed 0..127 | nd_j 0..127]
// w2P: [L][c2=8][kbg=16][lane][8]; natural k-order.
// ---------------------------------------------------------------------------
__global__ void k_convw(const float* __restrict__ w1, const float* __restrict__ w2,
                        ushort_t* __restrict__ w1P, ushort_t* __restrict__ w2P) {
    int idx = blockIdx.x * 256 + threadIdx.x;   // chunk index (8 elems each)
    if (idx < 65536) {
        int l = idx >> 14, r = idx & 16383;
        int c = r >> 9;  r &= 511;
        int kb = r >> 6, lane = r & 63;
        int col = c * 16 + (lane & 15);
        int k0 = kb * 32 + (lane >> 4) * 8;
        ushort_t o[8];
        #pragma unroll
        for (int e = 0; e < 8; ++e) {
            int kl = k0 + e;
            int row = kl < 128 ? kl : kl + 128;
            o[e] = f2b(w1[((size_t)l * 384 + row) * 512 + col]);
        }
        *(uint4*)(w1P + (size_t)idx * 8) = *(uint4*)o;
    }
    if (idx < 32768) {
        int l = idx >> 13, r = idx & 8191;
        int c2 = r >> 10; r &= 1023;
        int kbg = r >> 6, lane = r & 63;
        int col = c2 * 16 + (lane & 15);
        int k0 = kbg * 32 + (lane >> 4) * 8;
        ushort_t o[8];
        #pragma unroll
        for (int e = 0; e < 8; ++e)
            o[e] = f2b(w2[((size_t)l * 512 + k0 + e) * 128 + col]);
        *(uint4*)(w2P + (size_t)idx * 8) = *(uint4*)o;
    }
}

// ---------------------------------------------------------------------------
// Edge init: dist, adj, edges = relu(LN(dist*ee_w + ee_b)), edb bf16 mirror,
// and msgs_0 = adj * dot(edges_row, nodes[i]).   one wave per row.
// ---------------------------------------------------------------------------
__global__ void k_init(const float* __restrict__ coords, const float* __restrict__ nodes,
                       const float* __restrict__ ee_w, const float* __restrict__ ee_b,
                       const float* __restrict__ ee_g, const float* __restrict__ ee_bt,
                       float* __restrict__ ed, ushort_t* __restrict__ edb,
                       float* __restrict__ adjf, float* __restrict__ msgs) {
    int r = blockIdx.x * 4 + (threadIdx.x >> 6);
    int lane = threadIdx.x & 63;
    int i = r >> 8, j = r & 255;
    float dx = coords[i * 3 + 0] - coords[j * 3 + 0];
    float dy = coords[i * 3 + 1] - coords[j * 3 + 1];
    float dz = coords[i * 3 + 2] - coords[j * 3 + 2];
    float sq = dx * dx + dy * dy + dz * dz;
    float dist = sq > 0.f ? sqrtf(sq) : 0.f;
    float adjv = dist < 10.f ? 1.f : 0.f;
    if (lane == 0) adjf[r] = adjv;
    float e0 = dist * ee_w[lane] + ee_b[lane];
    float e1 = dist * ee_w[lane + 64] + ee_b[lane + 64];
    float s = e0 + e1, q = e0 * e0 + e1 * e1;
    #pragma unroll
    for (int off = 1; off < 64; off <<= 1) {
        s += __shfl_xor(s, off, 64);
        q += __shfl_xor(q, off, 64);
    }
    float mean = s * (1.f / 128.f);
    float var = q * (1.f / 128.f) - mean * mean;
    float rs = rsqrtf(var + LNEPS);
    float e0r = fmaxf((e0 - mean) * rs * ee_g[lane] + ee_bt[lane], 0.f);
    float e1r = fmaxf((e1 - mean) * rs * ee_g[lane + 64] + ee_bt[lane + 64], 0.f);
    ed[(size_t)r * 128 + lane]       = e0r;
    ed[(size_t)r * 128 + lane + 64]  = e1r;
    edb[(size_t)r * 128 + lane]      = f2b(e0r);
    edb[(size_t)r * 128 + lane + 64] = f2b(e1r);
    float d = e0r * nodes[(i << 7) + lane] + e1r * nodes[(i << 7) + 64 + lane];
    #pragma unroll
    for (int off = 1; off < 64; off <<= 1) d += __shfl_xor(d, off, 64);
    if (lane == 0) msgs[r] = adjv * d;
}

// ---------------------------------------------------------------------------
// Fused per-layer node work, 512 blocks:
//  blocks 0..255  : node MLP row r:  out = nd + relu(LN([nd|msgs]@W1n+b1n))@W2n+b2n
//  blocks 256..511: node precompute p: cI[p] = b1e + nd[p]@W1e[128:256];
//                   ndb[p] = bf16(nd[p])
// ---------------------------------------------------------------------------
__global__ __launch_bounds__(512) void k_node(
    const float* __restrict__ nd, const float* __restrict__ msgs,
    const float* __restrict__ W1n, const float* __restrict__ b1n,
    const float* __restrict__ gn, const float* __restrict__ btn,
    const float* __restrict__ W2n, const float* __restrict__ b2n,
    float* __restrict__ ndout,
    const float* __restrict__ W1e, const float* __restrict__ b1e,
    float* __restrict__ cI, ushort_t* __restrict__ ndb) {
    __shared__ float ni[512];
    __shared__ float hsh[512];
    __shared__ float part[4][128];
    __shared__ float red[16];
    int t = threadIdx.x;
    if (blockIdx.x >= 256) {
        // ---- precompute path
        int p = blockIdx.x - 256;
        if (t < 128) {
            float v = nd[(size_t)p * 128 + t];
            ni[t] = v;
            ndb[(size_t)p * 128 + t] = f2b(v);
        }
        __syncthreads();
        const float* wm = W1e + (size_t)128 * 512 + t;
        float a1 = b1e[t];
        #pragma unroll 4
        for (int k = 0; k < 128; ++k) a1 += ni[k] * wm[(size_t)k * 512];
        cI[(size_t)p * 512 + t] = a1;
        return;
    }
    // ---- node MLP path
    int row = blockIdx.x;
    if (t < 128) ni[t] = nd[(size_t)row * 128 + t];
    else if (t < 384) ni[t] = msgs[(size_t)row * 256 + (t - 128)];
    __syncthreads();
    float acc = b1n[t];
    #pragma unroll 4
    for (int k = 0; k < 384; ++k) acc += ni[k] * W1n[(size_t)k * 512 + t];
    float s = acc, q = acc * acc;
    #pragma unroll
    for (int off = 1; off < 64; off <<= 1) {
        s += __shfl_xor(s, off, 64);
        q += __shfl_xor(q, off, 64);
    }
    int wv = t >> 6;
    if ((t & 63) == 0) { red[wv] = s; red[8 + wv] = q; }
    __syncthreads();
    float S = 0.f, Q = 0.f;
    #pragma unroll
    for (int w = 0; w < 8; ++w) { S += red[w]; Q += red[8 + w]; }
    float mean = S * (1.f / 512.f);
    float var = Q * (1.f / 512.f) - mean * mean;
    float rs = rsqrtf(var + LNEPS);
    hsh[t] = fmaxf((acc - mean) * rs * gn[t] + btn[t], 0.f);
    __syncthreads();
    int qd = t >> 7, c = t & 127;
    float pacc = 0.f;
    #pragma unroll 4
    for (int kk = 0; kk < 128; ++kk)
        pacc += hsh[qd * 128 + kk] * W2n[(size_t)(qd * 128 + kk) * 128 + c];
    part[qd][c] = pacc;
    __syncthreads();
    if (t < 128) {
        float v = part[0][t] + part[1][t] + part[2][t] + part[3][t] + b2n[t]
                + nd[(size_t)row * 128 + t];
        ndout[(size_t)row * 128 + t] = v;
    }
}

// ---------------------------------------------------------------------------
// Generic fp32 row-MLP (tail heads): out = relu(LN(in @ W1 + b1)) @ W2 + b2
// ---------------------------------------------------------------------------
__global__ __launch_bounds__(512) void k_mlp(
    const float* __restrict__ in0, int w0,
    const float* __restrict__ W1, const float* __restrict__ b1,
    const float* __restrict__ g, const float* __restrict__ bt,
    const float* __restrict__ W2, const float* __restrict__ b2, int O,
    float* __restrict__ out) {
    __shared__ float ni[384];
    __shared__ float hsh[512];
    __shared__ float part[4][128];
    __shared__ float red[16];
    int row = blockIdx.x;
    int t = threadIdx.x;
    if (t < w0) ni[t] = in0[(size_t)row * w0 + t];
    __syncthreads();
    float acc = b1[t];
    #pragma unroll 4
    for (int k = 0; k < w0; ++k) acc += ni[k] * W1[(size_t)k * 512 + t];
    float s = acc, q = acc * acc;
    #pragma unroll
    for (int off = 1; off < 64; off <<= 1) {
        s += __shfl_xor(s, off, 64);
        q += __shfl_xor(q, off, 64);
    }
    int wv = t >> 6;
    if ((t & 63) == 0) { red[wv] = s; red[8 + wv] = q; }
    __syncthreads();
    float S = 0.f, Q = 0.f;
    #pragma unroll
    for (int w = 0; w < 8; ++w) { S += red[w]; Q += red[8 + w]; }
    float mean = S * (1.f / 512.f);
    float var = Q * (1.f / 512.f) - mean * mean;
    float rs = rsqrtf(var + LNEPS);
    hsh[t] = fmaxf((acc - mean) * rs * g[t] + bt[t], 0.f);
    __syncthreads();
    int qd = t >> 7, c = t & 127;
    float pacc = 0.f;
    if (c < O) {
        #pragma unroll 4
        for (int kk = 0; kk < 128; ++kk)
            pacc += hsh[qd * 128 + kk] * W2[(size_t)(qd * 128 + kk) * O + c];
    }
    part[qd][c] = pacc;
    __syncthreads();
    if (t < O) {
        float v = part[0][t] + part[1][t] + part[2][t] + part[3][t] + b2[t];
        out[(size_t)row * O + t] = v;
    }
}

// ---------------------------------------------------------------------------
// Fused edge update (in-place on ed + edb mirror) + msgs for next layer.
// bf16 MFMA, SWAPPED operand order: D[hidden-col][edge-row].
// Block: 512 threads (8 waves), 64 edge rows; i fixed, j = jbase + row.
// GEMM1: wave w -> 64 hidden cols, acc[4][4], kb-loop unroll 4 (deep B-load
//        pipelining -- the measured stall is L2 weight-load latency).
// GEMM2: K-split over two 32KB h-halves; acc2[4] carried across halves.
// LDS 36.5KB. __launch_bounds__(512,4): 128-reg budget (NOT 8 -- that forces
// a 64-reg budget and catastrophic spills, measured R8).
// ---------------------------------------------------------------------------
__global__ __launch_bounds__(512, 4) void k_edge(
    float* ed, ushort_t* edb, const ushort_t* __restrict__ ndb,
    const float* __restrict__ cIg, const ushort_t* __restrict__ w1P,
    const float* __restrict__ g, const float* __restrict__ bt,
    const ushort_t* __restrict__ w2P, const float* __restrict__ b2,
    const float* __restrict__ ndn, const float* __restrict__ adjf,
    float* __restrict__ msgs) {
    __shared__ char smem[37376];
    const int tid = threadIdx.x;
    const int w = tid >> 6, lane = tid & 63;
    const int l15 = lane & 15, lhi = lane >> 4;
    const int rbase = blockIdx.x * 64;
    const int ib = rbase >> 8;          // fixed node i for this block
    const int jbase = rbase & 255;

    // ---- stage ei = [edb | ndb] bf16 : 64 rows x 32 chunks(16B), XOR-swz row&7
    #pragma unroll
    for (int it = 0; it < 4; ++it) {
        int c = tid + it * 512;
        int row = c >> 5, q = c & 31;
        uint4 pk;
        if (q < 16) pk = *(const uint4*)(edb + (size_t)(rbase + row) * 128 + q * 8);
        else        pk = *(const uint4*)(ndb + (size_t)(jbase + row) * 128 + (q - 16) * 8);
        *(uint4*)(smem + row * 512 + ((q ^ (row & 7)) * 16)) = pk;
    }
    __syncthreads();

    // ---- GEMM1 (swapped): acc[m][n] = D[hcol][edgerow], K=256
    f32x4 acc[4][4];
    f32x4 zero = {0.f, 0.f, 0.f, 0.f};
    #pragma unroll
    for (int m = 0; m < 4; ++m)
        #pragma unroll
        for (int n = 0; n < 4; ++n) acc[m][n] = zero;

    const int cw = w * 64;
    #pragma unroll 4
    for (int kb = 0; kb < 8; ++kb) {
        short8 a[4];
        #pragma unroll
        for (int m = 0; m < 4; ++m) {
            int row = m * 16 + l15;
            a[m] = *(const short8*)(smem + row * 512 + (((kb * 4 + lhi) ^ (row & 7)) * 16));
        }
        #pragma unroll
        for (int n = 0; n < 4; ++n) {
            short8 b = *(const short8*)(w1P + ((((w * 4 + n) * 8 + kb) << 6) + lane) * 8);
            #pragma unroll
            for (int m = 0; m < 4; ++m)
                acc[m][n] = __builtin_amdgcn_mfma_f32_16x16x32_bf16(b, a[m], acc[m][n], 0, 0, 0);
        }
    }
    // acc[m][n][e]: edge row = m*16+l15, hidden col = cw + n*16 + lhi*4 + e

    // ---- add cI (float4, i fixed), per-row stats (rows in l15 -> 2 shfl only)
    float* red = (float*)(smem + 32768);     // [8][64][2]
    float* stats = (float*)(smem + 36864);   // [64][2]
    {
        float4 ci[4];
        #pragma unroll
        for (int n = 0; n < 4; ++n)
            ci[n] = *(const float4*)(cIg + (size_t)ib * 512 + cw + n * 16 + lhi * 4);
        #pragma unroll
        for (int m = 0; m < 4; ++m) {
            float s = 0.f, q = 0.f;
            #pragma unroll
            for (int n = 0; n < 4; ++n) {
                float v0 = acc[m][n][0] + ci[n].x;
                float v1 = acc[m][n][1] + ci[n].y;
                float v2 = acc[m][n][2] + ci[n].z;
                float v3 = acc[m][n][3] + ci[n].w;
                acc[m][n][0] = v0; acc[m][n][1] = v1;
                acc[m][n][2] = v2; acc[m][n][3] = v3;
                s += v0 + v1 + v2 + v3;
                q += v0 * v0 + v1 * v1 + v2 * v2 + v3 * v3;
            }
            s += __shfl_xor(s, 16, 64);
            s += __shfl_xor(s, 32, 64);
            q += __shfl_xor(q, 16, 64);
            q += __shfl_xor(q, 32, 64);
            if (lhi == 0) {
                red[(w * 64 + m * 16 + l15) * 2 + 0] = s;
                red[(w * 64 + m * 16 + l15) * 2 + 1] = q;
            }
        }
    }
    __syncthreads();
    if (tid < 64) {
        float S = 0.f, Q = 0.f;
        #pragma unroll
        for (int ww = 0; ww < 8; ++ww) {
            S += red[(ww * 64 + tid) * 2 + 0];
            Q += red[(ww * 64 + tid) * 2 + 1];
        }
        float mean = S * (1.f / 512.f);
        float var = Q * (1.f / 512.f) - mean * mean;
        stats[tid * 2 + 0] = mean;
        stats[tid * 2 + 1] = rsqrtf(var + LNEPS);
    }
    __syncthreads();

    // ---- LN apply + relu (in registers)
    {
        float4 gg[4], bb[4];
        #pragma unroll
        for (int n = 0; n < 4; ++n) {
            gg[n] = *(const float4*)(g + cw + n * 16 + lhi * 4);
            bb[n] = *(const float4*)(bt + cw + n * 16 + lhi * 4);
        }
        #pragma unroll
        for (int m = 0; m < 4; ++m) {
            int row = m * 16 + l15;
            float mean = stats[row * 2 + 0];
            float rs = stats[row * 2 + 1];
            #pragma unroll
            for (int n = 0; n < 4; ++n) {
                acc[m][n][0] = fmaxf((acc[m][n][0] - mean) * rs * gg[n].x + bb[n].x, 0.f);
                acc[m][n][1] = fmaxf((acc[m][n][1] - mean) * rs * gg[n].y + bb[n].y, 0.f);
                acc[m][n][2] = fmaxf((acc[m][n][2] - mean) * rs * gg[n].z + bb[n].z, 0.f);
                acc[m][n][3] = fmaxf((acc[m][n][3] - mean) * rs * gg[n].w + bb[n].w, 0.f);
            }
        }
    }

    // ---- GEMM2 (swapped), K-split over two h-halves; wave -> (rt, ch2)
    const int rt = w >> 1, ch2 = w & 1;
    const int arow = rt * 16 + l15;
    f32x4 acc2[4];
    #pragma unroll
    for (int n2 = 0; n2 < 4; ++n2) acc2[n2] = zero;

    #pragma unroll
    for (int hf = 0; hf < 2; ++hf) {
        // store h-half: waves with (w>>2)==hf own cols hf*256 .. hf*256+255
        if ((w >> 2) == hf) {
            const int base = (w & 3) * 64;
            #pragma unroll
            for (int m = 0; m < 4; ++m) {
                int row = m * 16 + l15;
                #pragma unroll
                for (int n = 0; n < 4; ++n) {
                    int p0 = base + n * 16 + lhi * 4;
                    int addr = row * 512 + ((((p0 >> 3) ^ (row & 7))) * 16) + (p0 & 7) * 2;
                    uint2 pk;
                    pk.x = (unsigned)f2b(acc[m][n][0]) | ((unsigned)f2b(acc[m][n][1]) << 16);
                    pk.y = (unsigned)f2b(acc[m][n][2]) | ((unsigned)f2b(acc[m][n][3]) << 16);
                    *(uint2*)(smem + addr) = pk;
                }
            }
        }
        __syncthreads();
        // GEMM2 partial: K = 256 of this half
        #pragma unroll 2
        for (int kbg = 0; kbg < 8; ++kbg) {
            short8 a = *(const short8*)(smem + arow * 512 + (((kbg * 4 + lhi) ^ (arow & 7)) * 16));
            #pragma unroll
            for (int n2 = 0; n2 < 4; ++n2) {
                short8 b = *(const short8*)(w2P + ((((ch2 * 4 + n2) * 16 + hf * 8 + kbg) << 6) + lane) * 8);
                acc2[n2] = __builtin_amdgcn_mfma_f32_16x16x32_bf16(b, a, acc2[n2], 0, 0, 0);
            }
        }
        __syncthreads();   // half's h reads done before overwrite / msum reuse
    }

    // ---- epilogue: float4 residual RMW, edb mirror, fused msgs partial
    float partial = 0.f;
    {
        const int row = rt * 16 + l15;
        #pragma unroll
        for (int n2 = 0; n2 < 4; ++n2) {
            int col0 = ch2 * 64 + n2 * 16 + lhi * 4;
            size_t goff = (size_t)(rbase + row) * 128 + col0;
            float4 r4 = *(const float4*)(ed + goff);
            float4 b4 = *(const float4*)(b2 + col0);
            float4 n4 = *(const float4*)(ndn + (size_t)ib * 128 + col0);
            float o0 = acc2[n2][0] + b4.x + r4.x;
            float o1 = acc2[n2][1] + b4.y + r4.y;
            float o2 = acc2[n2][2] + b4.z + r4.z;
            float o3 = acc2[n2][3] + b4.w + r4.w;
            float4 o4 = {o0, o1, o2, o3};
            *(float4*)(ed + goff) = o4;
            uint2 pk;
            pk.x = (unsigned)f2b(o0) | ((unsigned)f2b(o1) << 16);
            pk.y = (unsigned)f2b(o2) | ((unsigned)f2b(o3) << 16);
            *(uint2*)(edb + goff) = pk;
            partial += o0 * n4.x + o1 * n4.y + o2 * n4.z + o3 * n4.w;
        }
    }
    partial += __shfl_xor(partial, 16, 64);
    partial += __shfl_xor(partial, 32, 64);
    float* msum = (float*)(smem + 32768);   // reuse red region (dead)
    if (lhi == 0) msum[ch2 * 64 + rt * 16 + l15] = partial;
    __syncthreads();
    if (tid < 64) msgs[rbase + tid] = adjf[rbase + tid] * (msum[tid] + msum[64 + tid]);
}

// ---------------------------------------------------------------------------
extern "C" void kernel_launch(void* const* d_in, const int* in_sizes, int n_in,
                              void* d_out, int out_size, void* d_ws, size_t ws_size,
                              hipStream_t stream) {
    const float* nodes  = (const float*)d_in[0];
    const float* coords = (const float*)d_in[1];
    const float* ee_w   = (const float*)d_in[2];
    const float* ee_b   = (const float*)d_in[3];
    const float* ee_g   = (const float*)d_in[4];
    const float* ee_bt  = (const float*)d_in[5];
    const float* nu1_w  = (const float*)d_in[6];
    const float* nu1_b  = (const float*)d_in[7];
    const float* nu_g   = (const float*)d_in[8];
    const float* nu_bt  = (const float*)d_in[9];
    const float* nu2_w  = (const float*)d_in[10];
    const float* nu2_b  = (const float*)d_in[11];
    const float* eu1_w  = (const float*)d_in[12];
    const float* eu1_b  = (const float*)d_in[13];
    const float* eu_g   = (const float*)d_in[14];
    const float* eu_bt  = (const float*)d_in[15];
    const float* eu2_w  = (const float*)d_in[16];
    const float* eu2_b  = (const float*)d_in[17];
    const float* sp1_w  = (const float*)d_in[18];
    const float* sp1_b  = (const float*)d_in[19];
    const float* sp_g   = (const float*)d_in[20];
    const float* sp_bt  = (const float*)d_in[21];
    const float* sp2_w  = (const float*)d_in[22];
    const float* sp2_b  = (const float*)d_in[23];
    const float* no1_w  = (const float*)d_in[24];
    const float* no1_b  = (const float*)d_in[25];
    const float* no_g   = (const float*)d_in[26];
    const float* no_bt  = (const float*)d_in[27];
    const float* no2_w  = (const float*)d_in[28];
    const float* no2_b  = (const float*)d_in[29];

    char* p = (char*)d_ws;
    float* ed      = (float*)p;     p += (size_t)65536 * 128 * 4;   // 33.5 MB
    ushort_t* edb  = (ushort_t*)p;  p += (size_t)65536 * 128 * 2;   // 16.8 MB
    float* ndA     = (float*)p;     p += 256 * 128 * 4;
    float* ndB     = (float*)p;     p += 256 * 128 * 4;
    ushort_t* ndb  = (ushort_t*)p;  p += 256 * 128 * 2;
    float* msgs    = (float*)p;     p += 65536 * 4;
    float* adjf    = (float*)p;     p += 65536 * 4;
    float* cI      = (float*)p;     p += 256 * 512 * 4;
    ushort_t* w1P  = (ushort_t*)p;  p += (size_t)4 * 131072 * 2;    // 1 MB
    ushort_t* w2P  = (ushort_t*)p;  p += (size_t)4 * 65536 * 2;     // 512 KB

    k_convw<<<256, 256, 0, stream>>>(eu1_w, eu2_w, w1P, w2P);
    k_init<<<16384, 256, 0, stream>>>(coords, nodes, ee_w, ee_b, ee_g, ee_bt,
                                      ed, edb, adjf, msgs);

    const float* nd_cur = nodes;
    float* nd_bufs[2] = {ndA, ndB};
    for (int l = 0; l < 4; ++l) {
        float* nd_next = nd_bufs[l & 1];
        k_node<<<512, 512, 0, stream>>>(nd_cur, msgs,
            nu1_w + (size_t)l * 384 * 512, nu1_b + l * 512, nu_g + l * 512, nu_bt + l * 512,
            nu2_w + (size_t)l * 512 * 128, nu2_b + l * 128, nd_next,
            eu1_w + (size_t)l * 384 * 512, eu1_b + l * 512, cI, ndb);
        k_edge<<<1024, 512, 0, stream>>>(ed, edb, ndb, cI,
            w1P + (size_t)l * 131072, eu_g + l * 512, eu_bt + l * 512,
            w2P + (size_t)l * 65536, eu2_b + l * 128,
            nd_next, adjf, msgs);
        nd_cur = nd_next;
    }

    float* out_nodes  = (float*)d_out;
    float* out_coords = out_nodes + 32768;
    k_mlp<<<256, 512, 0, stream>>>(nd_cur, 128,
        no1_w, no1_b, no_g, no_bt, no2_w, no2_b, 128, out_nodes);
    k_mlp<<<256, 512, 0, stream>>>(out_nodes, 128,
        sp1_w, sp1_b, sp_g, sp_bt, sp2_w, sp2_b, 3, out_coords);
}

// Round 11
// 611.254 us; speedup vs baseline: 3.7982x; 1.0711x over previous
//
#include <hip/hip_runtime.h>

#define LNEPS 1e-5f

typedef unsigned short ushort_t;
typedef __attribute__((ext_vector_type(8))) short short8;   // bf16x8 MFMA frag
typedef __attribute__((ext_vector_type(4))) float f32x4;    // fp32x4 accum frag

__device__ inline unsigned short f2b(float f) {
    union { float f; unsigned int u; } c; c.f = f;
    unsigned int u = c.u;
    unsigned int r = (u + 0x7FFFu + ((u >> 16) & 1u)) >> 16;  // RNE
    return (unsigned short)r;
}

// ---------------------------------------------------------------------------
// Weight packing into MFMA fragment order (wave-contiguous 1KB loads).
// w1P: [L][c=32][kb=8][lane][8]; K=256 = [ed 0..127 | nd_j 0..127]
// w2P: [L][c2=8][kbg=16][lane][8]; natural k-order.
// ---------------------------------------------------------------------------
__global__ void k_convw(const float* __restrict__ w1, const float* __restrict__ w2,
                        ushort_t* __restrict__ w1P, ushort_t* __restrict__ w2P) {
    int idx = blockIdx.x * 256 + threadIdx.x;   // chunk index (8 elems each)
    if (idx < 65536) {
        int l = idx >> 14, r = idx & 16383;
        int c = r >> 9;  r &= 511;
        int kb = r >> 6, lane = r & 63;
        int col = c * 16 + (lane & 15);
        int k0 = kb * 32 + (lane >> 4) * 8;
        ushort_t o[8];
        #pragma unroll
        for (int e = 0; e < 8; ++e) {
            int kl = k0 + e;
            int row = kl < 128 ? kl : kl + 128;
            o[e] = f2b(w1[((size_t)l * 384 + row) * 512 + col]);
        }
        *(uint4*)(w1P + (size_t)idx * 8) = *(uint4*)o;
    }
    if (idx < 32768) {
        int l = idx >> 13, r = idx & 8191;
        int c2 = r >> 10; r &= 1023;
        int kbg = r >> 6, lane = r & 63;
        int col = c2 * 16 + (lane & 15);
        int k0 = kbg * 32 + (lane >> 4) * 8;
        ushort_t o[8];
        #pragma unroll
        for (int e = 0; e < 8; ++e)
            o[e] = f2b(w2[((size_t)l * 512 + k0 + e) * 128 + col]);
        *(uint4*)(w2P + (size_t)idx * 8) = *(uint4*)o;
    }
}

// ---------------------------------------------------------------------------
// Edge init: dist, adj, edges = relu(LN(dist*ee_w + ee_b)), edb bf16 mirror,
// and msgs_0 = adj * dot(edges_row, nodes[i]).   one wave per row.
// ---------------------------------------------------------------------------
__global__ void k_init(const float* __restrict__ coords, const float* __restrict__ nodes,
                       const float* __restrict__ ee_w, const float* __restrict__ ee_b,
                       const float* __restrict__ ee_g, const float* __restrict__ ee_bt,
                       float* __restrict__ ed, ushort_t* __restrict__ edb,
                       float* __restrict__ adjf, float* __restrict__ msgs) {
    int r = blockIdx.x * 4 + (threadIdx.x >> 6);
    int lane = threadIdx.x & 63;
    int i = r >> 8, j = r & 255;
    float dx = coords[i * 3 + 0] - coords[j * 3 + 0];
    float dy = coords[i * 3 + 1] - coords[j * 3 + 1];
    float dz = coords[i * 3 + 2] - coords[j * 3 + 2];
    float sq = dx * dx + dy * dy + dz * dz;
    float dist = sq > 0.f ? sqrtf(sq) : 0.f;
    float adjv = dist < 10.f ? 1.f : 0.f;
    if (lane == 0) adjf[r] = adjv;
    float e0 = dist * ee_w[lane] + ee_b[lane];
    float e1 = dist * ee_w[lane + 64] + ee_b[lane + 64];
    float s = e0 + e1, q = e0 * e0 + e1 * e1;
    #pragma unroll
    for (int off = 1; off < 64; off <<= 1) {
        s += __shfl_xor(s, off, 64);
        q += __shfl_xor(q, off, 64);
    }
    float mean = s * (1.f / 128.f);
    float var = q * (1.f / 128.f) - mean * mean;
    float rs = rsqrtf(var + LNEPS);
    float e0r = fmaxf((e0 - mean) * rs * ee_g[lane] + ee_bt[lane], 0.f);
    float e1r = fmaxf((e1 - mean) * rs * ee_g[lane + 64] + ee_bt[lane + 64], 0.f);
    ed[(size_t)r * 128 + lane]       = e0r;
    ed[(size_t)r * 128 + lane + 64]  = e1r;
    edb[(size_t)r * 128 + lane]      = f2b(e0r);
    edb[(size_t)r * 128 + lane + 64] = f2b(e1r);
    float d = e0r * nodes[(i << 7) + lane] + e1r * nodes[(i << 7) + 64 + lane];
    #pragma unroll
    for (int off = 1; off < 64; off <<= 1) d += __shfl_xor(d, off, 64);
    if (lane == 0) msgs[r] = adjv * d;
}

// ---------------------------------------------------------------------------
// Fused per-layer node work, 512 blocks:
//  blocks 0..255  : node MLP row r:  out = nd + relu(LN([nd|msgs]@W1n+b1n))@W2n+b2n
//  blocks 256..511: node precompute p: cI[p] = b1e + nd[p]@W1e[128:256];
//                   ndb[p] = bf16(nd[p])
// ---------------------------------------------------------------------------
__global__ __launch_bounds__(512) void k_node(
    const float* __restrict__ nd, const float* __restrict__ msgs,
    const float* __restrict__ W1n, const float* __restrict__ b1n,
    const float* __restrict__ gn, const float* __restrict__ btn,
    const float* __restrict__ W2n, const float* __restrict__ b2n,
    float* __restrict__ ndout,
    const float* __restrict__ W1e, const float* __restrict__ b1e,
    float* __restrict__ cI, ushort_t* __restrict__ ndb) {
    __shared__ float ni[512];
    __shared__ float hsh[512];
    __shared__ float part[4][128];
    __shared__ float red[16];
    int t = threadIdx.x;
    if (blockIdx.x >= 256) {
        // ---- precompute path
        int p = blockIdx.x - 256;
        if (t < 128) {
            float v = nd[(size_t)p * 128 + t];
            ni[t] = v;
            ndb[(size_t)p * 128 + t] = f2b(v);
        }
        __syncthreads();
        const float* wm = W1e + (size_t)128 * 512 + t;
        float a1 = b1e[t];
        #pragma unroll 4
        for (int k = 0; k < 128; ++k) a1 += ni[k] * wm[(size_t)k * 512];
        cI[(size_t)p * 512 + t] = a1;
        return;
    }
    // ---- node MLP path
    int row = blockIdx.x;
    if (t < 128) ni[t] = nd[(size_t)row * 128 + t];
    else if (t < 384) ni[t] = msgs[(size_t)row * 256 + (t - 128)];
    __syncthreads();
    float acc = b1n[t];
    #pragma unroll 4
    for (int k = 0; k < 384; ++k) acc += ni[k] * W1n[(size_t)k * 512 + t];
    float s = acc, q = acc * acc;
    #pragma unroll
    for (int off = 1; off < 64; off <<= 1) {
        s += __shfl_xor(s, off, 64);
        q += __shfl_xor(q, off, 64);
    }
    int wv = t >> 6;
    if ((t & 63) == 0) { red[wv] = s; red[8 + wv] = q; }
    __syncthreads();
    float S = 0.f, Q = 0.f;
    #pragma unroll
    for (int w = 0; w < 8; ++w) { S += red[w]; Q += red[8 + w]; }
    float mean = S * (1.f / 512.f);
    float var = Q * (1.f / 512.f) - mean * mean;
    float rs = rsqrtf(var + LNEPS);
    hsh[t] = fmaxf((acc - mean) * rs * gn[t] + btn[t], 0.f);
    __syncthreads();
    int qd = t >> 7, c = t & 127;
    float pacc = 0.f;
    #pragma unroll 4
    for (int kk = 0; kk < 128; ++kk)
        pacc += hsh[qd * 128 + kk] * W2n[(size_t)(qd * 128 + kk) * 128 + c];
    part[qd][c] = pacc;
    __syncthreads();
    if (t < 128) {
        float v = part[0][t] + part[1][t] + part[2][t] + part[3][t] + b2n[t]
                + nd[(size_t)row * 128 + t];
        ndout[(size_t)row * 128 + t] = v;
    }
}

// ---------------------------------------------------------------------------
// Generic fp32 row-MLP (tail heads): out = relu(LN(in @ W1 + b1)) @ W2 + b2
// ---------------------------------------------------------------------------
__global__ __launch_bounds__(512) void k_mlp(
    const float* __restrict__ in0, int w0,
    const float* __restrict__ W1, const float* __restrict__ b1,
    const float* __restrict__ g, const float* __restrict__ bt,
    const float* __restrict__ W2, const float* __restrict__ b2, int O,
    float* __restrict__ out) {
    __shared__ float ni[384];
    __shared__ float hsh[512];
    __shared__ float part[4][128];
    __shared__ float red[16];
    int row = blockIdx.x;
    int t = threadIdx.x;
    if (t < w0) ni[t] = in0[(size_t)row * w0 + t];
    __syncthreads();
    float acc = b1[t];
    #pragma unroll 4
    for (int k = 0; k < w0; ++k) acc += ni[k] * W1[(size_t)k * 512 + t];
    float s = acc, q = acc * acc;
    #pragma unroll
    for (int off = 1; off < 64; off <<= 1) {
        s += __shfl_xor(s, off, 64);
        q += __shfl_xor(q, off, 64);
    }
    int wv = t >> 6;
    if ((t & 63) == 0) { red[wv] = s; red[8 + wv] = q; }
    __syncthreads();
    float S = 0.f, Q = 0.f;
    #pragma unroll
    for (int w = 0; w < 8; ++w) { S += red[w]; Q += red[8 + w]; }
    float mean = S * (1.f / 512.f);
    float var = Q * (1.f / 512.f) - mean * mean;
    float rs = rsqrtf(var + LNEPS);
    hsh[t] = fmaxf((acc - mean) * rs * g[t] + bt[t], 0.f);
    __syncthreads();
    int qd = t >> 7, c = t & 127;
    float pacc = 0.f;
    if (c < O) {
        #pragma unroll 4
        for (int kk = 0; kk < 128; ++kk)
            pacc += hsh[qd * 128 + kk] * W2[(size_t)(qd * 128 + kk) * O + c];
    }
    part[qd][c] = pacc;
    __syncthreads();
    if (t < O) {
        float v = part[0][t] + part[1][t] + part[2][t] + part[3][t] + b2[t];
        out[(size_t)row * O + t] = v;
    }
}

// ---------------------------------------------------------------------------
// Fused edge update (in-place on ed + edb mirror) + msgs for next layer.
// bf16 MFMA, SWAPPED operand order: D[hidden-col][edge-row].
// Block: 512 threads (8 waves), 64 edge rows; i fixed, j = jbase + row.
// GEMM1: wave w -> 64 hidden cols, acc[4][4], unroll 2 (R5/R7-proven).
// GEMM2: single pass, full h [64][512]bf16 = 64KB, 16 kbg, acc2[4].
// Epilogue via LDS outstage [64][132] fp32 (padded) -> LINEAR writeout:
//   thread t -> row t>>3, cols (t&7)*16: ed RMW 4x float4 (full-line streams),
//   edb 2x uint4, msgs partial via 8-lane shuffle. Fixes the measured 2x
//   write amplification of scattered 32B edb stores (R7/R9: WRITE 101MB vs 50).
// LDS 70144: stage 32KB / h 64KB / outstage 33.8KB (reuse) + red/stats/msum.
// __launch_bounds__(512,4): 128-reg budget (8 spills catastrophically -- R8).
// ---------------------------------------------------------------------------
__global__ __launch_bounds__(512, 4) void k_edge(
    float* ed, ushort_t* edb, const ushort_t* __restrict__ ndb,
    const float* __restrict__ cIg, const ushort_t* __restrict__ w1P,
    const float* __restrict__ g, const float* __restrict__ bt,
    const ushort_t* __restrict__ w2P, const float* __restrict__ b2,
    const float* __restrict__ ndn, const float* __restrict__ adjf,
    float* __restrict__ msgs) {
    __shared__ char smem[70144];
    const int tid = threadIdx.x;
    const int w = tid >> 6, lane = tid & 63;
    const int l15 = lane & 15, lhi = lane >> 4;
    const int rbase = blockIdx.x * 64;
    const int ib = rbase >> 8;          // fixed node i for this block
    const int jbase = rbase & 255;

    // ---- stage ei = [edb | ndb] bf16 : 64 rows x 32 chunks(16B), XOR-swz row&7
    #pragma unroll
    for (int it = 0; it < 4; ++it) {
        int c = tid + it * 512;
        int row = c >> 5, q = c & 31;
        uint4 pk;
        if (q < 16) pk = *(const uint4*)(edb + (size_t)(rbase + row) * 128 + q * 8);
        else        pk = *(const uint4*)(ndb + (size_t)(jbase + row) * 128 + (q - 16) * 8);
        *(uint4*)(smem + row * 512 + ((q ^ (row & 7)) * 16)) = pk;
    }
    __syncthreads();

    // ---- GEMM1 (swapped): acc[m][n] = D[hcol][edgerow], K=256
    f32x4 acc[4][4];
    f32x4 zero = {0.f, 0.f, 0.f, 0.f};
    #pragma unroll
    for (int m = 0; m < 4; ++m)
        #pragma unroll
        for (int n = 0; n < 4; ++n) acc[m][n] = zero;

    const int cw = w * 64;
    #pragma unroll 2
    for (int kb = 0; kb < 8; ++kb) {
        short8 a[4];
        #pragma unroll
        for (int m = 0; m < 4; ++m) {
            int row = m * 16 + l15;
            a[m] = *(const short8*)(smem + row * 512 + (((kb * 4 + lhi) ^ (row & 7)) * 16));
        }
        #pragma unroll
        for (int n = 0; n < 4; ++n) {
            short8 b = *(const short8*)(w1P + ((((w * 4 + n) * 8 + kb) << 6) + lane) * 8);
            #pragma unroll
            for (int m = 0; m < 4; ++m)
                acc[m][n] = __builtin_amdgcn_mfma_f32_16x16x32_bf16(b, a[m], acc[m][n], 0, 0, 0);
        }
    }
    // acc[m][n][e]: edge row = m*16+l15, hidden col = cw + n*16 + lhi*4 + e

    // ---- add cI (float4, i fixed), per-row stats (rows in l15 -> 2 shfl only)
    float* red = (float*)(smem + 65536);     // [8][64][2]
    float* stats = (float*)(smem + 69632);   // [64][2]
    {
        float4 ci[4];
        #pragma unroll
        for (int n = 0; n < 4; ++n)
            ci[n] = *(const float4*)(cIg + (size_t)ib * 512 + cw + n * 16 + lhi * 4);
        #pragma unroll
        for (int m = 0; m < 4; ++m) {
            float s = 0.f, q = 0.f;
            #pragma unroll
            for (int n = 0; n < 4; ++n) {
                float v0 = acc[m][n][0] + ci[n].x;
                float v1 = acc[m][n][1] + ci[n].y;
                float v2 = acc[m][n][2] + ci[n].z;
                float v3 = acc[m][n][3] + ci[n].w;
                acc[m][n][0] = v0; acc[m][n][1] = v1;
                acc[m][n][2] = v2; acc[m][n][3] = v3;
                s += v0 + v1 + v2 + v3;
                q += v0 * v0 + v1 * v1 + v2 * v2 + v3 * v3;
            }
            s += __shfl_xor(s, 16, 64);
            s += __shfl_xor(s, 32, 64);
            q += __shfl_xor(q, 16, 64);
            q += __shfl_xor(q, 32, 64);
            if (lhi == 0) {
                red[(w * 64 + m * 16 + l15) * 2 + 0] = s;
                red[(w * 64 + m * 16 + l15) * 2 + 1] = q;
            }
        }
    }
    __syncthreads();
    if (tid < 64) {
        float S = 0.f, Q = 0.f;
        #pragma unroll
        for (int ww = 0; ww < 8; ++ww) {
            S += red[(ww * 64 + tid) * 2 + 0];
            Q += red[(ww * 64 + tid) * 2 + 1];
        }
        float mean = S * (1.f / 512.f);
        float var = Q * (1.f / 512.f) - mean * mean;
        stats[tid * 2 + 0] = mean;
        stats[tid * 2 + 1] = rsqrtf(var + LNEPS);
    }
    __syncthreads();

    // ---- LN apply + relu, h -> LDS bf16 [64][1024B] XOR-swz (overwrites stage)
    {
        float4 gg[4], bb[4];
        #pragma unroll
        for (int n = 0; n < 4; ++n) {
            gg[n] = *(const float4*)(g + cw + n * 16 + lhi * 4);
            bb[n] = *(const float4*)(bt + cw + n * 16 + lhi * 4);
        }
        #pragma unroll
        for (int m = 0; m < 4; ++m) {
            int row = m * 16 + l15;
            float mean = stats[row * 2 + 0];
            float rs = stats[row * 2 + 1];
            #pragma unroll
            for (int n = 0; n < 4; ++n) {
                float v0 = fmaxf((acc[m][n][0] - mean) * rs * gg[n].x + bb[n].x, 0.f);
                float v1 = fmaxf((acc[m][n][1] - mean) * rs * gg[n].y + bb[n].y, 0.f);
                float v2 = fmaxf((acc[m][n][2] - mean) * rs * gg[n].z + bb[n].z, 0.f);
                float v3 = fmaxf((acc[m][n][3] - mean) * rs * gg[n].w + bb[n].w, 0.f);
                int p0 = cw + n * 16 + lhi * 4;
                int addr = row * 1024 + ((((p0 >> 3) ^ (row & 7))) * 16) + (p0 & 7) * 2;
                uint2 pk;
                pk.x = (unsigned)f2b(v0) | ((unsigned)f2b(v1) << 16);
                pk.y = (unsigned)f2b(v2) | ((unsigned)f2b(v3) << 16);
                *(uint2*)(smem + addr) = pk;
            }
        }
    }
    __syncthreads();

    // ---- GEMM2 (swapped, single pass): wave (rt,ch2); D[w2col][edgerow], K=512
    const int rt = w >> 1, ch2 = w & 1;
    f32x4 acc2[4];
    #pragma unroll
    for (int n2 = 0; n2 < 4; ++n2) acc2[n2] = zero;
    const int arow = rt * 16 + l15;
    #pragma unroll 2
    for (int kbg = 0; kbg < 16; ++kbg) {
        short8 a = *(const short8*)(smem + arow * 1024 + (((kbg * 4 + lhi) ^ (arow & 7)) * 16));
        #pragma unroll
        for (int n2 = 0; n2 < 4; ++n2) {
            short8 b = *(const short8*)(w2P + ((((ch2 * 4 + n2) * 16 + kbg) << 6) + lane) * 8);
            acc2[n2] = __builtin_amdgcn_mfma_f32_16x16x32_bf16(b, a, acc2[n2], 0, 0, 0);
        }
    }
    __syncthreads();   // h reads done; reuse region as fp32 outstage

    // ---- outstage: acc2 + b2 -> LDS fp32 [64][132] (pad 4 -> 2-way banks max)
    float* outs = (float*)smem;
    {
        const int row = rt * 16 + l15;
        #pragma unroll
        for (int n2 = 0; n2 < 4; ++n2) {
            int col0 = ch2 * 64 + n2 * 16 + lhi * 4;
            float4 b4 = *(const float4*)(b2 + col0);
            float4 o4 = {acc2[n2][0] + b4.x, acc2[n2][1] + b4.y,
                         acc2[n2][2] + b4.z, acc2[n2][3] + b4.w};
            *(float4*)(outs + (size_t)row * 132 + col0) = o4;
        }
    }
    __syncthreads();

    // ---- linear writeout: thread t -> row t>>3, cols (t&7)*16 .. +16
    {
        const int row = tid >> 3, col0 = (tid & 7) * 16;
        const size_t goff = (size_t)(rbase + row) * 128 + col0;
        const float* src = outs + (size_t)row * 132 + col0;
        const float* nsr = ndn + (size_t)ib * 128 + col0;
        float o[16];
        float partial = 0.f;
        #pragma unroll
        for (int c = 0; c < 4; ++c) {
            float4 s4 = *(const float4*)(src + c * 4);
            float4 r4 = *(const float4*)(ed + goff + c * 4);
            float4 n4 = *(const float4*)(nsr + c * 4);
            o[c * 4 + 0] = s4.x + r4.x;
            o[c * 4 + 1] = s4.y + r4.y;
            o[c * 4 + 2] = s4.z + r4.z;
            o[c * 4 + 3] = s4.w + r4.w;
            partial += o[c * 4 + 0] * n4.x + o[c * 4 + 1] * n4.y
                     + o[c * 4 + 2] * n4.z + o[c * 4 + 3] * n4.w;
            *(float4*)(ed + goff + c * 4) = *(float4*)(o + c * 4);
        }
        uint4 pk0, pk1;
        pk0.x = (unsigned)f2b(o[0])  | ((unsigned)f2b(o[1])  << 16);
        pk0.y = (unsigned)f2b(o[2])  | ((unsigned)f2b(o[3])  << 16);
        pk0.z = (unsigned)f2b(o[4])  | ((unsigned)f2b(o[5])  << 16);
        pk0.w = (unsigned)f2b(o[6])  | ((unsigned)f2b(o[7])  << 16);
        pk1.x = (unsigned)f2b(o[8])  | ((unsigned)f2b(o[9])  << 16);
        pk1.y = (unsigned)f2b(o[10]) | ((unsigned)f2b(o[11]) << 16);
        pk1.z = (unsigned)f2b(o[12]) | ((unsigned)f2b(o[13]) << 16);
        pk1.w = (unsigned)f2b(o[14]) | ((unsigned)f2b(o[15]) << 16);
        *(uint4*)(edb + goff)     = pk0;
        *(uint4*)(edb + goff + 8) = pk1;
        // msgs: reduce 8 threads of this row (adjacent lanes)
        partial += __shfl_xor(partial, 1, 64);
        partial += __shfl_xor(partial, 2, 64);
        partial += __shfl_xor(partial, 4, 64);
        float* msum = (float*)(smem + 65536);   // red region (dead)
        if ((tid & 7) == 0) msum[row] = partial;
        __syncthreads();
        if (tid < 64) msgs[rbase + tid] = adjf[rbase + tid] * msum[tid];
    }
}

// ---------------------------------------------------------------------------
extern "C" void kernel_launch(void* const* d_in, const int* in_sizes, int n_in,
                              void* d_out, int out_size, void* d_ws, size_t ws_size,
                              hipStream_t stream) {
    const float* nodes  = (const float*)d_in[0];
    const float* coords = (const float*)d_in[1];
    const float* ee_w   = (const float*)d_in[2];
    const float* ee_b   = (const float*)d_in[3];
    const float* ee_g   = (const float*)d_in[4];
    const float* ee_bt  = (const float*)d_in[5];
    const float* nu1_w  = (const float*)d_in[6];
    const float* nu1_b  = (const float*)d_in[7];
    const float* nu_g   = (const float*)d_in[8];
    const float* nu_bt  = (const float*)d_in[9];
    const float* nu2_w  = (const float*)d_in[10];
    const float* nu2_b  = (const float*)d_in[11];
    const float* eu1_w  = (const float*)d_in[12];
    const float* eu1_b  = (const float*)d_in[13];
    const float* eu_g   = (const float*)d_in[14];
    const float* eu_bt  = (const float*)d_in[15];
    const float* eu2_w  = (const float*)d_in[16];
    const float* eu2_b  = (const float*)d_in[17];
    const float* sp1_w  = (const float*)d_in[18];
    const float* sp1_b  = (const float*)d_in[19];
    const float* sp_g   = (const float*)d_in[20];
    const float* sp_bt  = (const float*)d_in[21];
    const float* sp2_w  = (const float*)d_in[22];
    const float* sp2_b  = (const float*)d_in[23];
    const float* no1_w  = (const float*)d_in[24];
    const float* no1_b  = (const float*)d_in[25];
    const float* no_g   = (const float*)d_in[26];
    const float* no_bt  = (const float*)d_in[27];
    const float* no2_w  = (const float*)d_in[28];
    const float* no2_b  = (const float*)d_in[29];

    char* p = (char*)d_ws;
    float* ed      = (float*)p;     p += (size_t)65536 * 128 * 4;   // 33.5 MB
    ushort_t* edb  = (ushort_t*)p;  p += (size_t)65536 * 128 * 2;   // 16.8 MB
    float* ndA     = (float*)p;     p += 256 * 128 * 4;
    float* ndB     = (float*)p;     p += 256 * 128 * 4;
    ushort_t* ndb  = (ushort_t*)p;  p += 256 * 128 * 2;
    float* msgs    = (float*)p;     p += 65536 * 4;
    float* adjf    = (float*)p;     p += 65536 * 4;
    float* cI      = (float*)p;     p += 256 * 512 * 4;
    ushort_t* w1P  = (ushort_t*)p;  p += (size_t)4 * 131072 * 2;    // 1 MB
    ushort_t* w2P  = (ushort_t*)p;  p += (size_t)4 * 65536 * 2;     // 512 KB

    k_convw<<<256, 256, 0, stream>>>(eu1_w, eu2_w, w1P, w2P);
    k_init<<<16384, 256, 0, stream>>>(coords, nodes, ee_w, ee_b, ee_g, ee_bt,
                                      ed, edb, adjf, msgs);

    const float* nd_cur = nodes;
    float* nd_bufs[2] = {ndA, ndB};
    for (int l = 0; l < 4; ++l) {
        float* nd_next = nd_bufs[l & 1];
        k_node<<<512, 512, 0, stream>>>(nd_cur, msgs,
            nu1_w + (size_t)l * 384 * 512, nu1_b + l * 512, nu_g + l * 512, nu_bt + l * 512,
            nu2_w + (size_t)l * 512 * 128, nu2_b + l * 128, nd_next,
            eu1_w + (size_t)l * 384 * 512, eu1_b + l * 512, cI, ndb);
        k_edge<<<1024, 512, 0, stream>>>(ed, edb, ndb, cI,
            w1P + (size_t)l * 131072, eu_g + l * 512, eu_bt + l * 512,
            w2P + (size_t)l * 65536, eu2_b + l * 128,
            nd_next, adjf, msgs);
        nd_cur = nd_next;
    }

    float* out_nodes  = (float*)d_out;
    float* out_coords = out_nodes + 32768;
    k_mlp<<<256, 512, 0, stream>>>(nd_cur, 128,
        no1_w, no1_b, no_g, no_bt, no2_w, no2_b, 128, out_nodes);
    k_mlp<<<256, 512, 0, stream>>>(out_nodes, 128,
        sp1_w, sp1_b, sp_g, sp_bt, sp2_w, sp2_b, 3, out_coords);
}

// Round 12
// 598.415 us; speedup vs baseline: 3.8797x; 1.0215x over previous
//
#include <hip/hip_runtime.h>

#define LNEPS 1e-5f

typedef unsigned short ushort_t;
typedef __attribute__((ext_vector_type(8))) short short8;   // bf16x8 MFMA frag
typedef __attribute__((ext_vector_type(4))) float f32x4;    // fp32x4 accum frag

__device__ inline unsigned short f2b(float f) {
    union { float f; unsigned int u; } c; c.f = f;
    unsigned int u = c.u;
    unsigned int r = (u + 0x7FFFu + ((u >> 16) & 1u)) >> 16;  // RNE
    return (unsigned short)r;
}
__device__ inline float b2f_lo(unsigned u) { union { unsigned u; float f; } c; c.u = u << 16; return c.f; }
__device__ inline float b2f_hi(unsigned u) { union { unsigned u; float f; } c; c.u = u & 0xFFFF0000u; return c.f; }

// ---------------------------------------------------------------------------
// Weight packing into MFMA fragment order (wave-contiguous 1KB loads).
// w1P: [L][c=32][kb=8][lane][8]; K=256 = [ed 0..127 | nd_j 0..127]
// w2P: [L][c2=8][kbg=16][lane][8]; natural k-order.
// ---------------------------------------------------------------------------
__global__ void k_convw(const float* __restrict__ w1, const float* __restrict__ w2,
                        ushort_t* __restrict__ w1P, ushort_t* __restrict__ w2P) {
    int idx = blockIdx.x * 256 + threadIdx.x;   // chunk index (8 elems each)
    if (idx < 65536) {
        int l = idx >> 14, r = idx & 16383;
        int c = r >> 9;  r &= 511;
        int kb = r >> 6, lane = r & 63;
        int col = c * 16 + (lane & 15);
        int k0 = kb * 32 + (lane >> 4) * 8;
        ushort_t o[8];
        #pragma unroll
        for (int e = 0; e < 8; ++e) {
            int kl = k0 + e;
            int row = kl < 128 ? kl : kl + 128;
            o[e] = f2b(w1[((size_t)l * 384 + row) * 512 + col]);
        }
        *(uint4*)(w1P + (size_t)idx * 8) = *(uint4*)o;
    }
    if (idx < 32768) {
        int l = idx >> 13, r = idx & 8191;
        int c2 = r >> 10; r &= 1023;
        int kbg = r >> 6, lane = r & 63;
        int col = c2 * 16 + (lane & 15);
        int k0 = kbg * 32 + (lane >> 4) * 8;
        ushort_t o[8];
        #pragma unroll
        for (int e = 0; e < 8; ++e)
            o[e] = f2b(w2[((size_t)l * 512 + k0 + e) * 128 + col]);
        *(uint4*)(w2P + (size_t)idx * 8) = *(uint4*)o;
    }
}

// ---------------------------------------------------------------------------
// Edge init: edges = relu(LN(dist*ee_w + ee_b)) -> edb (bf16 ONLY; fp32 edge
// state eliminated -- edges are internal, discarded by the reference), adj,
// msgs_0 = adj * dot(edges_row, nodes[i]).   one wave per row.
// ---------------------------------------------------------------------------
__global__ void k_init(const float* __restrict__ coords, const float* __restrict__ nodes,
                       const float* __restrict__ ee_w, const float* __restrict__ ee_b,
                       const float* __restrict__ ee_g, const float* __restrict__ ee_bt,
                       ushort_t* __restrict__ edb,
                       float* __restrict__ adjf, float* __restrict__ msgs) {
    int r = blockIdx.x * 4 + (threadIdx.x >> 6);
    int lane = threadIdx.x & 63;
    int i = r >> 8, j = r & 255;
    float dx = coords[i * 3 + 0] - coords[j * 3 + 0];
    float dy = coords[i * 3 + 1] - coords[j * 3 + 1];
    float dz = coords[i * 3 + 2] - coords[j * 3 + 2];
    float sq = dx * dx + dy * dy + dz * dz;
    float dist = sq > 0.f ? sqrtf(sq) : 0.f;
    float adjv = dist < 10.f ? 1.f : 0.f;
    if (lane == 0) adjf[r] = adjv;
    float e0 = dist * ee_w[lane] + ee_b[lane];
    float e1 = dist * ee_w[lane + 64] + ee_b[lane + 64];
    float s = e0 + e1, q = e0 * e0 + e1 * e1;
    #pragma unroll
    for (int off = 1; off < 64; off <<= 1) {
        s += __shfl_xor(s, off, 64);
        q += __shfl_xor(q, off, 64);
    }
    float mean = s * (1.f / 128.f);
    float var = q * (1.f / 128.f) - mean * mean;
    float rs = rsqrtf(var + LNEPS);
    float e0r = fmaxf((e0 - mean) * rs * ee_g[lane] + ee_bt[lane], 0.f);
    float e1r = fmaxf((e1 - mean) * rs * ee_g[lane + 64] + ee_bt[lane + 64], 0.f);
    edb[(size_t)r * 128 + lane]      = f2b(e0r);
    edb[(size_t)r * 128 + lane + 64] = f2b(e1r);
    float d = e0r * nodes[(i << 7) + lane] + e1r * nodes[(i << 7) + 64 + lane];
    #pragma unroll
    for (int off = 1; off < 64; off <<= 1) d += __shfl_xor(d, off, 64);
    if (lane == 0) msgs[r] = adjv * d;
}

// ---------------------------------------------------------------------------
// Fused per-layer node work, 512 blocks:
//  blocks 0..255  : node MLP row r:  out = nd + relu(LN([nd|msgs]@W1n+b1n))@W2n+b2n
//  blocks 256..511: node precompute p: cI[p] = b1e + nd[p]@W1e[128:256];
//                   ndb[p] = bf16(nd[p])
// ---------------------------------------------------------------------------
__global__ __launch_bounds__(512) void k_node(
    const float* __restrict__ nd, const float* __restrict__ msgs,
    const float* __restrict__ W1n, const float* __restrict__ b1n,
    const float* __restrict__ gn, const float* __restrict__ btn,
    const float* __restrict__ W2n, const float* __restrict__ b2n,
    float* __restrict__ ndout,
    const float* __restrict__ W1e, const float* __restrict__ b1e,
    float* __restrict__ cI, ushort_t* __restrict__ ndb) {
    __shared__ float ni[512];
    __shared__ float hsh[512];
    __shared__ float part[4][128];
    __shared__ float red[16];
    int t = threadIdx.x;
    if (blockIdx.x >= 256) {
        // ---- precompute path
        int p = blockIdx.x - 256;
        if (t < 128) {
            float v = nd[(size_t)p * 128 + t];
            ni[t] = v;
            ndb[(size_t)p * 128 + t] = f2b(v);
        }
        __syncthreads();
        const float* wm = W1e + (size_t)128 * 512 + t;
        float a1 = b1e[t];
        #pragma unroll 4
        for (int k = 0; k < 128; ++k) a1 += ni[k] * wm[(size_t)k * 512];
        cI[(size_t)p * 512 + t] = a1;
        return;
    }
    // ---- node MLP path
    int row = blockIdx.x;
    if (t < 128) ni[t] = nd[(size_t)row * 128 + t];
    else if (t < 384) ni[t] = msgs[(size_t)row * 256 + (t - 128)];
    __syncthreads();
    float acc = b1n[t];
    #pragma unroll 4
    for (int k = 0; k < 384; ++k) acc += ni[k] * W1n[(size_t)k * 512 + t];
    float s = acc, q = acc * acc;
    #pragma unroll
    for (int off = 1; off < 64; off <<= 1) {
        s += __shfl_xor(s, off, 64);
        q += __shfl_xor(q, off, 64);
    }
    int wv = t >> 6;
    if ((t & 63) == 0) { red[wv] = s; red[8 + wv] = q; }
    __syncthreads();
    float S = 0.f, Q = 0.f;
    #pragma unroll
    for (int w = 0; w < 8; ++w) { S += red[w]; Q += red[8 + w]; }
    float mean = S * (1.f / 512.f);
    float var = Q * (1.f / 512.f) - mean * mean;
    float rs = rsqrtf(var + LNEPS);
    hsh[t] = fmaxf((acc - mean) * rs * gn[t] + btn[t], 0.f);
    __syncthreads();
    int qd = t >> 7, c = t & 127;
    float pacc = 0.f;
    #pragma unroll 4
    for (int kk = 0; kk < 128; ++kk)
        pacc += hsh[qd * 128 + kk] * W2n[(size_t)(qd * 128 + kk) * 128 + c];
    part[qd][c] = pacc;
    __syncthreads();
    if (t < 128) {
        float v = part[0][t] + part[1][t] + part[2][t] + part[3][t] + b2n[t]
                + nd[(size_t)row * 128 + t];
        ndout[(size_t)row * 128 + t] = v;
    }
}

// ---------------------------------------------------------------------------
// Generic fp32 row-MLP (tail heads): out = relu(LN(in @ W1 + b1)) @ W2 + b2
// ---------------------------------------------------------------------------
__global__ __launch_bounds__(512) void k_mlp(
    const float* __restrict__ in0, int w0,
    const float* __restrict__ W1, const float* __restrict__ b1,
    const float* __restrict__ g, const float* __restrict__ bt,
    const float* __restrict__ W2, const float* __restrict__ b2, int O,
    float* __restrict__ out) {
    __shared__ float ni[384];
    __shared__ float hsh[512];
    __shared__ float part[4][128];
    __shared__ float red[16];
    int row = blockIdx.x;
    int t = threadIdx.x;
    if (t < w0) ni[t] = in0[(size_t)row * w0 + t];
    __syncthreads();
    float acc = b1[t];
    #pragma unroll 4
    for (int k = 0; k < w0; ++k) acc += ni[k] * W1[(size_t)k * 512 + t];
    float s = acc, q = acc * acc;
    #pragma unroll
    for (int off = 1; off < 64; off <<= 1) {
        s += __shfl_xor(s, off, 64);
        q += __shfl_xor(q, off, 64);
    }
    int wv = t >> 6;
    if ((t & 63) == 0) { red[wv] = s; red[8 + wv] = q; }
    __syncthreads();
    float S = 0.f, Q = 0.f;
    #pragma unroll
    for (int w = 0; w < 8; ++w) { S += red[w]; Q += red[8 + w]; }
    float mean = S * (1.f / 512.f);
    float var = Q * (1.f / 512.f) - mean * mean;
    float rs = rsqrtf(var + LNEPS);
    hsh[t] = fmaxf((acc - mean) * rs * g[t] + bt[t], 0.f);
    __syncthreads();
    int qd = t >> 7, c = t & 127;
    float pacc = 0.f;
    if (c < O) {
        #pragma unroll 4
        for (int kk = 0; kk < 128; ++kk)
            pacc += hsh[qd * 128 + kk] * W2[(size_t)(qd * 128 + kk) * O + c];
    }
    part[qd][c] = pacc;
    __syncthreads();
    if (t < O) {
        float v = part[0][t] + part[1][t] + part[2][t] + part[3][t] + b2[t];
        out[(size_t)row * O + t] = v;
    }
}

// ---------------------------------------------------------------------------
// Fused edge update (bf16 state ONLY, in-place on edb) + msgs for next layer.
// bf16 MFMA, SWAPPED operand order: D[hidden-col][edge-row].
// Block: 512 threads (8 waves), 64 edge rows; i fixed, j = jbase + row.
// Residual: snapshotted from staged LDS into 8 VGPRs before h overwrites it
//   -> NO fp32 ed buffer, no 33.5MB RMW read + 67MB write on the hot path.
// GEMM1: wave w -> 64 hidden cols, acc[4][4], unroll 2.
// GEMM2: single pass, full h [64][512]bf16 = 64KB, 16 kbg, acc2[4].
// Epilogue: outstage acc2+b2 -> LDS fp32 [64][132] -> linear writeout
//   (thread t -> row t>>3, cols (t&7)*16): add reg-residual, store edb 2x
//   uint4, msgs partial via 8-lane shuffle.
// LDS 70144. __launch_bounds__(512,4): 128-reg budget (8 spills -- R8).
// ---------------------------------------------------------------------------
__global__ __launch_bounds__(512, 4) void k_edge(
    ushort_t* edb, const ushort_t* __restrict__ ndb,
    const float* __restrict__ cIg, const ushort_t* __restrict__ w1P,
    const float* __restrict__ g, const float* __restrict__ bt,
    const ushort_t* __restrict__ w2P, const float* __restrict__ b2,
    const float* __restrict__ ndn, const float* __restrict__ adjf,
    float* __restrict__ msgs) {
    __shared__ char smem[70144];
    const int tid = threadIdx.x;
    const int w = tid >> 6, lane = tid & 63;
    const int l15 = lane & 15, lhi = lane >> 4;
    const int rbase = blockIdx.x * 64;
    const int ib = rbase >> 8;          // fixed node i for this block
    const int jbase = rbase & 255;

    // ---- stage ei = [edb | ndb] bf16 : 64 rows x 32 chunks(16B), XOR-swz row&7
    #pragma unroll
    for (int it = 0; it < 4; ++it) {
        int c = tid + it * 512;
        int row = c >> 5, q = c & 31;
        uint4 pk;
        if (q < 16) pk = *(const uint4*)(edb + (size_t)(rbase + row) * 128 + q * 8);
        else        pk = *(const uint4*)(ndb + (size_t)(jbase + row) * 128 + (q - 16) * 8);
        *(uint4*)(smem + row * 512 + ((q ^ (row & 7)) * 16)) = pk;
    }
    __syncthreads();

    // ---- residual snapshot into regs (stage region dies at the h-store)
    // thread t owns epilogue row t>>3, cols (t&7)*16..+15 = chunks 2*(t&7), +1
    uint4 res0, res1;
    {
        const int row = tid >> 3, q0 = (tid & 7) * 2;
        res0 = *(const uint4*)(smem + row * 512 + ((q0 ^ (row & 7)) * 16));
        res1 = *(const uint4*)(smem + row * 512 + (((q0 + 1) ^ (row & 7)) * 16));
    }

    // ---- GEMM1 (swapped): acc[m][n] = D[hcol][edgerow], K=256
    f32x4 acc[4][4];
    f32x4 zero = {0.f, 0.f, 0.f, 0.f};
    #pragma unroll
    for (int m = 0; m < 4; ++m)
        #pragma unroll
        for (int n = 0; n < 4; ++n) acc[m][n] = zero;

    const int cw = w * 64;
    #pragma unroll 2
    for (int kb = 0; kb < 8; ++kb) {
        short8 a[4];
        #pragma unroll
        for (int m = 0; m < 4; ++m) {
            int row = m * 16 + l15;
            a[m] = *(const short8*)(smem + row * 512 + (((kb * 4 + lhi) ^ (row & 7)) * 16));
        }
        #pragma unroll
        for (int n = 0; n < 4; ++n) {
            short8 b = *(const short8*)(w1P + ((((w * 4 + n) * 8 + kb) << 6) + lane) * 8);
            #pragma unroll
            for (int m = 0; m < 4; ++m)
                acc[m][n] = __builtin_amdgcn_mfma_f32_16x16x32_bf16(b, a[m], acc[m][n], 0, 0, 0);
        }
    }
    // acc[m][n][e]: edge row = m*16+l15, hidden col = cw + n*16 + lhi*4 + e

    // ---- add cI (float4, i fixed), per-row stats (rows in l15 -> 2 shfl only)
    float* red = (float*)(smem + 65536);     // [8][64][2]
    float* stats = (float*)(smem + 69632);   // [64][2]
    {
        float4 ci[4];
        #pragma unroll
        for (int n = 0; n < 4; ++n)
            ci[n] = *(const float4*)(cIg + (size_t)ib * 512 + cw + n * 16 + lhi * 4);
        #pragma unroll
        for (int m = 0; m < 4; ++m) {
            float s = 0.f, q = 0.f;
            #pragma unroll
            for (int n = 0; n < 4; ++n) {
                float v0 = acc[m][n][0] + ci[n].x;
                float v1 = acc[m][n][1] + ci[n].y;
                float v2 = acc[m][n][2] + ci[n].z;
                float v3 = acc[m][n][3] + ci[n].w;
                acc[m][n][0] = v0; acc[m][n][1] = v1;
                acc[m][n][2] = v2; acc[m][n][3] = v3;
                s += v0 + v1 + v2 + v3;
                q += v0 * v0 + v1 * v1 + v2 * v2 + v3 * v3;
            }
            s += __shfl_xor(s, 16, 64);
            s += __shfl_xor(s, 32, 64);
            q += __shfl_xor(q, 16, 64);
            q += __shfl_xor(q, 32, 64);
            if (lhi == 0) {
                red[(w * 64 + m * 16 + l15) * 2 + 0] = s;
                red[(w * 64 + m * 16 + l15) * 2 + 1] = q;
            }
        }
    }
    __syncthreads();
    if (tid < 64) {
        float S = 0.f, Q = 0.f;
        #pragma unroll
        for (int ww = 0; ww < 8; ++ww) {
            S += red[(ww * 64 + tid) * 2 + 0];
            Q += red[(ww * 64 + tid) * 2 + 1];
        }
        float mean = S * (1.f / 512.f);
        float var = Q * (1.f / 512.f) - mean * mean;
        stats[tid * 2 + 0] = mean;
        stats[tid * 2 + 1] = rsqrtf(var + LNEPS);
    }
    __syncthreads();

    // ---- LN apply + relu, h -> LDS bf16 [64][1024B] XOR-swz (overwrites stage)
    {
        float4 gg[4], bb[4];
        #pragma unroll
        for (int n = 0; n < 4; ++n) {
            gg[n] = *(const float4*)(g + cw + n * 16 + lhi * 4);
            bb[n] = *(const float4*)(bt + cw + n * 16 + lhi * 4);
        }
        #pragma unroll
        for (int m = 0; m < 4; ++m) {
            int row = m * 16 + l15;
            float mean = stats[row * 2 + 0];
            float rs = stats[row * 2 + 1];
            #pragma unroll
            for (int n = 0; n < 4; ++n) {
                float v0 = fmaxf((acc[m][n][0] - mean) * rs * gg[n].x + bb[n].x, 0.f);
                float v1 = fmaxf((acc[m][n][1] - mean) * rs * gg[n].y + bb[n].y, 0.f);
                float v2 = fmaxf((acc[m][n][2] - mean) * rs * gg[n].z + bb[n].z, 0.f);
                float v3 = fmaxf((acc[m][n][3] - mean) * rs * gg[n].w + bb[n].w, 0.f);
                int p0 = cw + n * 16 + lhi * 4;
                int addr = row * 1024 + ((((p0 >> 3) ^ (row & 7))) * 16) + (p0 & 7) * 2;
                uint2 pk;
                pk.x = (unsigned)f2b(v0) | ((unsigned)f2b(v1) << 16);
                pk.y = (unsigned)f2b(v2) | ((unsigned)f2b(v3) << 16);
                *(uint2*)(smem + addr) = pk;
            }
        }
    }
    __syncthreads();

    // ---- GEMM2 (swapped, single pass): wave (rt,ch2); D[w2col][edgerow], K=512
    const int rt = w >> 1, ch2 = w & 1;
    f32x4 acc2[4];
    #pragma unroll
    for (int n2 = 0; n2 < 4; ++n2) acc2[n2] = zero;
    const int arow = rt * 16 + l15;
    #pragma unroll 2
    for (int kbg = 0; kbg < 16; ++kbg) {
        short8 a = *(const short8*)(smem + arow * 1024 + (((kbg * 4 + lhi) ^ (arow & 7)) * 16));
        #pragma unroll
        for (int n2 = 0; n2 < 4; ++n2) {
            short8 b = *(const short8*)(w2P + ((((ch2 * 4 + n2) * 16 + kbg) << 6) + lane) * 8);
            acc2[n2] = __builtin_amdgcn_mfma_f32_16x16x32_bf16(b, a, acc2[n2], 0, 0, 0);
        }
    }
    __syncthreads();   // h reads done; reuse region as fp32 outstage

    // ---- outstage: acc2 + b2 -> LDS fp32 [64][132] (pad 4 -> 2-way banks max)
    float* outs = (float*)smem;
    {
        const int row = rt * 16 + l15;
        #pragma unroll
        for (int n2 = 0; n2 < 4; ++n2) {
            int col0 = ch2 * 64 + n2 * 16 + lhi * 4;
            float4 b4 = *(const float4*)(b2 + col0);
            float4 o4 = {acc2[n2][0] + b4.x, acc2[n2][1] + b4.y,
                         acc2[n2][2] + b4.z, acc2[n2][3] + b4.w};
            *(float4*)(outs + (size_t)row * 132 + col0) = o4;
        }
    }
    __syncthreads();

    // ---- linear writeout: thread t -> row t>>3, cols (t&7)*16 .. +16
    {
        const int row = tid >> 3, col0 = (tid & 7) * 16;
        const size_t goff = (size_t)(rbase + row) * 128 + col0;
        const float* src = outs + (size_t)row * 132 + col0;
        const float* nsr = ndn + (size_t)ib * 128 + col0;
        unsigned ru[8] = {res0.x, res0.y, res0.z, res0.w,
                          res1.x, res1.y, res1.z, res1.w};
        float o[16];
        float partial = 0.f;
        #pragma unroll
        for (int c = 0; c < 4; ++c) {
            float4 s4 = *(const float4*)(src + c * 4);
            float4 n4 = *(const float4*)(nsr + c * 4);
            o[c * 4 + 0] = s4.x + b2f_lo(ru[c * 2]);
            o[c * 4 + 1] = s4.y + b2f_hi(ru[c * 2]);
            o[c * 4 + 2] = s4.z + b2f_lo(ru[c * 2 + 1]);
            o[c * 4 + 3] = s4.w + b2f_hi(ru[c * 2 + 1]);
            partial += o[c * 4 + 0] * n4.x + o[c * 4 + 1] * n4.y
                     + o[c * 4 + 2] * n4.z + o[c * 4 + 3] * n4.w;
        }
        uint4 pk0, pk1;
        pk0.x = (unsigned)f2b(o[0])  | ((unsigned)f2b(o[1])  << 16);
        pk0.y = (unsigned)f2b(o[2])  | ((unsigned)f2b(o[3])  << 16);
        pk0.z = (unsigned)f2b(o[4])  | ((unsigned)f2b(o[5])  << 16);
        pk0.w = (unsigned)f2b(o[6])  | ((unsigned)f2b(o[7])  << 16);
        pk1.x = (unsigned)f2b(o[8])  | ((unsigned)f2b(o[9])  << 16);
        pk1.y = (unsigned)f2b(o[10]) | ((unsigned)f2b(o[11]) << 16);
        pk1.z = (unsigned)f2b(o[12]) | ((unsigned)f2b(o[13]) << 16);
        pk1.w = (unsigned)f2b(o[14]) | ((unsigned)f2b(o[15]) << 16);
        *(uint4*)(edb + goff)     = pk0;
        *(uint4*)(edb + goff + 8) = pk1;
        // msgs: reduce 8 threads of this row (adjacent lanes)
        partial += __shfl_xor(partial, 1, 64);
        partial += __shfl_xor(partial, 2, 64);
        partial += __shfl_xor(partial, 4, 64);
        float* msum = (float*)(smem + 65536);   // red region (dead)
        if ((tid & 7) == 0) msum[row] = partial;
        __syncthreads();
        if (tid < 64) msgs[rbase + tid] = adjf[rbase + tid] * msum[tid];
    }
}

// ---------------------------------------------------------------------------
extern "C" void kernel_launch(void* const* d_in, const int* in_sizes, int n_in,
                              void* d_out, int out_size, void* d_ws, size_t ws_size,
                              hipStream_t stream) {
    const float* nodes  = (const float*)d_in[0];
    const float* coords = (const float*)d_in[1];
    const float* ee_w   = (const float*)d_in[2];
    const float* ee_b   = (const float*)d_in[3];
    const float* ee_g   = (const float*)d_in[4];
    const float* ee_bt  = (const float*)d_in[5];
    const float* nu1_w  = (const float*)d_in[6];
    const float* nu1_b  = (const float*)d_in[7];
    const float* nu_g   = (const float*)d_in[8];
    const float* nu_bt  = (const float*)d_in[9];
    const float* nu2_w  = (const float*)d_in[10];
    const float* nu2_b  = (const float*)d_in[11];
    const float* eu1_w  = (const float*)d_in[12];
    const float* eu1_b  = (const float*)d_in[13];
    const float* eu_g   = (const float*)d_in[14];
    const float* eu_bt  = (const float*)d_in[15];
    const float* eu2_w  = (const float*)d_in[16];
    const float* eu2_b  = (const float*)d_in[17];
    const float* sp1_w  = (const float*)d_in[18];
    const float* sp1_b  = (const float*)d_in[19];
    const float* sp_g   = (const float*)d_in[20];
    const float* sp_bt  = (const float*)d_in[21];
    const float* sp2_w  = (const float*)d_in[22];
    const float* sp2_b  = (const float*)d_in[23];
    const float* no1_w  = (const float*)d_in[24];
    const float* no1_b  = (const float*)d_in[25];
    const float* no_g   = (const float*)d_in[26];
    const float* no_bt  = (const float*)d_in[27];
    const float* no2_w  = (const float*)d_in[28];
    const float* no2_b  = (const float*)d_in[29];

    char* p = (char*)d_ws;
    ushort_t* edb  = (ushort_t*)p;  p += (size_t)65536 * 128 * 2;   // 16.8 MB (sole edge state)
    float* ndA     = (float*)p;     p += 256 * 128 * 4;
    float* ndB     = (float*)p;     p += 256 * 128 * 4;
    ushort_t* ndb  = (ushort_t*)p;  p += 256 * 128 * 2;
    float* msgs    = (float*)p;     p += 65536 * 4;
    float* adjf    = (float*)p;     p += 65536 * 4;
    float* cI      = (float*)p;     p += 256 * 512 * 4;
    ushort_t* w1P  = (ushort_t*)p;  p += (size_t)4 * 131072 * 2;    // 1 MB
    ushort_t* w2P  = (ushort_t*)p;  p += (size_t)4 * 65536 * 2;     // 512 KB

    k_convw<<<256, 256, 0, stream>>>(eu1_w, eu2_w, w1P, w2P);
    k_init<<<16384, 256, 0, stream>>>(coords, nodes, ee_w, ee_b, ee_g, ee_bt,
                                      edb, adjf, msgs);

    const float* nd_cur = nodes;
    float* nd_bufs[2] = {ndA, ndB};
    for (int l = 0; l < 4; ++l) {
        float* nd_next = nd_bufs[l & 1];
        k_node<<<512, 512, 0, stream>>>(nd_cur, msgs,
            nu1_w + (size_t)l * 384 * 512, nu1_b + l * 512, nu_g + l * 512, nu_bt + l * 512,
            nu2_w + (size_t)l * 512 * 128, nu2_b + l * 128, nd_next,
            eu1_w + (size_t)l * 384 * 512, eu1_b + l * 512, cI, ndb);
        k_edge<<<1024, 512, 0, stream>>>(edb, ndb, cI,
            w1P + (size_t)l * 131072, eu_g + l * 512, eu_bt + l * 512,
            w2P + (size_t)l * 65536, eu2_b + l * 128,
            nd_next, adjf, msgs);
        nd_cur = nd_next;
    }

    float* out_nodes  = (float*)d_out;
    float* out_coords = out_nodes + 32768;
    k_mlp<<<256, 512, 0, stream>>>(nd_cur, 128,
        no1_w, no1_b, no_g, no_bt, no2_w, no2_b, 128, out_nodes);
    k_mlp<<<256, 512, 0, stream>>>(out_nodes, 128,
        sp1_w, sp1_b, sp_g, sp_bt, sp2_w, sp2_b, 3, out_coords);
}